// Round 1
// baseline (1040.459 us; speedup 1.0000x reference)
//
#include <hip/hip_runtime.h>

constexpr int NN = 50000;    // nodes per type
constexpr int NE = 600000;   // edges per type
constexpr int HH = 128;      // hidden
constexpr int GG = 64;       // graphs
constexpr int LL = 2;        // layers
constexpr int OC = 16;       // out channels
constexpr float NEG = 0.2f;

// ---------- precompute v = W @ att (8 vectors of 128) ----------
__global__ void k_prevec(const float* __restrict__ Wsrc, const float* __restrict__ Wdst,
                         const float* __restrict__ att_src, const float* __restrict__ att_dst,
                         float* __restrict__ v) {
    int b = blockIdx.x;            // 0..7 : kind = b>>2 (0=src,1=dst), lt = b&3
    int kind = b >> 2, lt = b & 3;
    const float* W   = (kind ? Wdst : Wsrc) + (size_t)lt * HH * HH;
    const float* att = (kind ? att_dst : att_src) + lt * HH;
    __shared__ float sa[HH];
    int t = threadIdx.x;           // 128 threads
    sa[t] = att[t];
    __syncthreads();
    float s = 0.f;
    for (int j = 0; j < HH; ++j) s += W[t * HH + j] * sa[j];
    v[b * HH + t] = s;
}

// ---------- CSR build ----------
__global__ void k_hist(const int* __restrict__ dst, int* __restrict__ cnt, int e) {
    int i = blockIdx.x * blockDim.x + threadIdx.x;
    if (i < e) atomicAdd(&cnt[dst[i]], 1);
}

__global__ void k_scan1(const int* __restrict__ cnt, int* __restrict__ bsum, int n) {
    __shared__ int s[256];
    int i = blockIdx.x * 256 + threadIdx.x;
    s[threadIdx.x] = (i < n) ? cnt[i] : 0;
    __syncthreads();
    for (int off = 128; off > 0; off >>= 1) {
        if (threadIdx.x < off) s[threadIdx.x] += s[threadIdx.x + off];
        __syncthreads();
    }
    if (threadIdx.x == 0) bsum[blockIdx.x] = s[0];
}

__global__ void k_scan2(int* __restrict__ bsum, int nb) {   // one block of 256: exclusive scan in place
    __shared__ int s[256];
    int t = threadIdx.x;
    int v = (t < nb) ? bsum[t] : 0;
    s[t] = v;
    __syncthreads();
    for (int off = 1; off < 256; off <<= 1) {
        int x = (t >= off) ? s[t - off] : 0;
        __syncthreads();
        s[t] += x;
        __syncthreads();
    }
    if (t < nb) bsum[t] = s[t] - v;   // exclusive
}

__global__ void k_scan3(const int* __restrict__ cnt, const int* __restrict__ bsum,
                        int* __restrict__ rowptr, int n, int e) {
    __shared__ int s[256];
    int t = threadIdx.x;
    int i = blockIdx.x * 256 + t;
    int v = (i < n) ? cnt[i] : 0;
    s[t] = v;
    __syncthreads();
    for (int off = 1; off < 256; off <<= 1) {
        int x = (t >= off) ? s[t - off] : 0;
        __syncthreads();
        s[t] += x;
        __syncthreads();
    }
    if (i < n) rowptr[i] = bsum[blockIdx.x] + s[t] - v;
    if (i == n - 1) rowptr[n] = e;
}

__global__ void k_scatter(const int* __restrict__ src, const int* __restrict__ dst,
                          int* __restrict__ cursor, int* __restrict__ col, int e) {
    int i = blockIdx.x * blockDim.x + threadIdx.x;
    if (i < e) {
        int d = dst[i];
        int p = atomicAdd(&cursor[d], 1);
        col[p] = src[i];
    }
}

// ---------- a = X . v1, X . v2 (one wave per node) ----------
__global__ __launch_bounds__(256) void k_dualdot(const float* __restrict__ X,
                                                 const float* __restrict__ v1,
                                                 const float* __restrict__ v2,
                                                 float* __restrict__ o1, float* __restrict__ o2, int n) {
    int wid  = (blockIdx.x * blockDim.x + threadIdx.x) >> 6;
    int lane = threadIdx.x & 63;
    if (wid >= n) return;
    float2 x = *(const float2*)(X + (size_t)wid * HH + lane * 2);
    float2 a = *(const float2*)(v1 + lane * 2);
    float2 b = *(const float2*)(v2 + lane * 2);
    float s1 = x.x * a.x + x.y * a.y;
    float s2 = x.x * b.x + x.y * b.y;
    for (int off = 32; off; off >>= 1) {
        s1 += __shfl_xor(s1, off);
        s2 += __shfl_xor(s2, off);
    }
    if (lane == 0) { o1[wid] = s1; o2[wid] = s2; }
}

// ---------- H = X @ W  (fp32, W staged in LDS in K-halves, X transposed in LDS) ----------
__global__ __launch_bounds__(256) void k_gemm(const float* __restrict__ X, const float* __restrict__ W,
                                              float* __restrict__ Hout, int n) {
    __shared__ float Wl[64 * HH];   // 32 KB: W rows kh..kh+63
    __shared__ float Xt[HH * 32];   // 16 KB: transposed [k][r]
    int t = threadIdx.x;
    int r0 = blockIdx.x * 32;

    // stage X tile transposed (coalesced global read)
    for (int f = t; f < 1024; f += 256) {          // 1024 float4 = 32 rows * 32 f4
        int r = f >> 5, k4 = (f & 31) << 2;
        int gr = r0 + r;
        float4 xv = (gr < n) ? *(const float4*)(X + (size_t)gr * HH + k4)
                             : make_float4(0.f, 0.f, 0.f, 0.f);
        Xt[(k4 + 0) * 32 + r] = xv.x;
        Xt[(k4 + 1) * 32 + r] = xv.y;
        Xt[(k4 + 2) * 32 + r] = xv.z;
        Xt[(k4 + 3) * 32 + r] = xv.w;
    }

    int jj = t & 31, rr = t >> 5;
    int c0 = jj * 4, rbase = rr * 4;
    float acc[4][4] = {};

    for (int kh = 0; kh < HH; kh += 64) {
        // stage W rows [kh, kh+64)
        for (int i = t; i < 64 * HH / 4; i += 256)
            ((float4*)Wl)[i] = ((const float4*)(W + (size_t)kh * HH))[i];
        __syncthreads();
        for (int kk = 0; kk < 64; kk += 4) {
#pragma unroll
            for (int q = 0; q < 4; ++q) {
                const float4 wv = *(const float4*)(Wl + (kk + q) * HH + c0);
                const float4 xv = *(const float4*)(Xt + (kh + kk + q) * 32 + rbase);
                acc[0][0] += xv.x * wv.x; acc[0][1] += xv.x * wv.y; acc[0][2] += xv.x * wv.z; acc[0][3] += xv.x * wv.w;
                acc[1][0] += xv.y * wv.x; acc[1][1] += xv.y * wv.y; acc[1][2] += xv.y * wv.z; acc[1][3] += xv.y * wv.w;
                acc[2][0] += xv.z * wv.x; acc[2][1] += xv.z * wv.y; acc[2][2] += xv.z * wv.z; acc[2][3] += xv.z * wv.w;
                acc[3][0] += xv.w * wv.x; acc[3][1] += xv.w * wv.y; acc[3][2] += xv.w * wv.z; acc[3][3] += xv.w * wv.w;
            }
        }
        __syncthreads();
    }

#pragma unroll
    for (int i = 0; i < 4; ++i) {
        int gr = r0 + rbase + i;
        if (gr < n) {
            float4 o = make_float4(acc[i][0], acc[i][1], acc[i][2], acc[i][3]);
            *(float4*)(Hout + (size_t)gr * HH + c0) = o;
        }
    }
}

// ---------- GAT aggregation: one wave per destination node ----------
__global__ __launch_bounds__(256) void k_aggregate(const int* __restrict__ rowptr, const int* __restrict__ col,
                                                   const float* __restrict__ Hs, const float* __restrict__ a_s,
                                                   const float* __restrict__ a_d, const float* __restrict__ bias,
                                                   float* __restrict__ Xout, int n) {
    int w = (blockIdx.x * blockDim.x + threadIdx.x) >> 6;
    int lane = threadIdx.x & 63;
    if (w >= n) return;
    int base = rowptr[w], end = rowptr[w + 1];
    float add = a_d[w];

    // pass 1: segment max (lanes parallel over edges)
    float m = -1e30f;
    for (int j = base + lane; j < end; j += 64) {
        float sc = a_s[col[j]] + add;
        sc = sc > 0.f ? sc : NEG * sc;
        m = fmaxf(m, sc);
    }
    for (int off = 32; off; off >>= 1) m = fmaxf(m, __shfl_xor(m, off));

    // pass 2: weighted accumulate (lanes parallel over features)
    float den = 0.f;
    float2 acc = {0.f, 0.f};
    for (int j = base; j < end; ++j) {
        int s = col[j];                       // wave-uniform
        float sc = a_s[s] + add;
        sc = sc > 0.f ? sc : NEG * sc;
        float ex = __expf(sc - m);
        den += ex;
        float2 h = *(const float2*)(Hs + (size_t)s * HH + lane * 2);
        acc.x += ex * h.x;
        acc.y += ex * h.y;
    }
    float inv = 1.f / (den + 1e-16f);
    float2 b = *(const float2*)(bias + lane * 2);
    float2 o;
    o.x = fmaxf(acc.x * inv + b.x, 0.f);
    o.y = fmaxf(acc.y * inv + b.y, 0.f);
    *(float2*)(Xout + (size_t)w * HH + lane * 2) = o;
}

// ---------- pooling: segment_max over sorted batch (relu'd values >= 0 -> uint atomicMax) ----------
constexpr int POOL_CHUNK = 512;
__global__ void k_pool(const float* __restrict__ X, const int* __restrict__ batch,
                       unsigned* __restrict__ pooled, int n) {
    int f = threadIdx.x;     // 128 threads = one feature each
    int n0 = blockIdx.x * POOL_CHUNK;
    if (n0 >= n) return;
    int n1 = min(n0 + POOL_CHUNK, n);
    int g = batch[n0];
    float m = 0.f;
    for (int i = n0; i < n1; ++i) {
        int gi = batch[i];
        if (gi != g) {
            atomicMax(&pooled[g * HH + f], __float_as_uint(m));
            m = 0.f;
            g = gi;
        }
        m = fmaxf(m, X[(size_t)i * HH + f]);
    }
    atomicMax(&pooled[g * HH + f], __float_as_uint(m));
}

// ---------- final linear: [2][64][128] @ [128][16] + b ----------
__global__ void k_final(const unsigned* __restrict__ pooled, const float* __restrict__ linW,
                        const float* __restrict__ linb, float* __restrict__ out) {
    int idx = blockIdx.x * blockDim.x + threadIdx.x;
    if (idx >= 2 * GG * OC) return;
    int p = idx >> 10;            // which node type
    int g = (idx >> 4) & 63;
    int o = idx & 15;
    const unsigned* row = pooled + (size_t)(p * GG + g) * HH;
    float s = linb[o];
    for (int k = 0; k < HH; ++k) s += __uint_as_float(row[k]) * linW[k * OC + o];
    out[idx] = s;
}

extern "C" void kernel_launch(void* const* d_in, const int* in_sizes, int n_in,
                              void* d_out, int out_size, void* d_ws, size_t ws_size,
                              hipStream_t stream) {
    const float* x_paper  = (const float*)d_in[0];
    const float* x_author = (const float*)d_in[1];
    const int*   edge_pa  = (const int*)d_in[2];   // [2][E], row0=src(paper), row1=dst(author)
    const int*   edge_ap  = (const int*)d_in[3];
    const int*   batch_p  = (const int*)d_in[4];
    const int*   batch_a  = (const int*)d_in[5];
    const float* Wsrc     = (const float*)d_in[6];
    const float* Wdst     = (const float*)d_in[7];
    const float* att_src  = (const float*)d_in[8];
    const float* att_dst  = (const float*)d_in[9];
    const float* bias     = (const float*)d_in[10];
    const float* linW     = (const float*)d_in[11];
    const float* linb     = (const float*)d_in[12];
    float* out = (float*)d_out;

    size_t off = 0;
    char* base = (char*)d_ws;
    auto alloc = [&](size_t bytes) -> void* {
        void* p = base + off;
        off += (bytes + 255) & ~(size_t)255;
        return p;
    };
    float* H0  = (float*)alloc((size_t)NN * HH * 4);
    float* H1  = (float*)alloc((size_t)NN * HH * 4);
    float* XP  = (float*)alloc((size_t)NN * HH * 4);
    float* XA  = (float*)alloc((size_t)NN * HH * 4);
    float* as0 = (float*)alloc(NN * 4);
    float* ad0 = (float*)alloc(NN * 4);
    float* as1 = (float*)alloc(NN * 4);
    float* ad1 = (float*)alloc(NN * 4);
    float* vv  = (float*)alloc(8 * HH * 4);
    int* rp_pa  = (int*)alloc((NN + 1) * 4);
    int* rp_ap  = (int*)alloc((NN + 1) * 4);
    int* col_pa = (int*)alloc(NE * 4);
    int* col_ap = (int*)alloc(NE * 4);
    int* cnt    = (int*)alloc((NN + 1) * 4);
    int* bsum   = (int*)alloc(1024);
    unsigned* pooled = (unsigned*)alloc(2 * GG * HH * 4);

    const int EB  = (NE + 255) / 256;        // 2344
    const int NBS = (NN + 255) / 256;        // 196

    // ---- precompute attention vectors ----
    k_prevec<<<8, 128, 0, stream>>>(Wsrc, Wdst, att_src, att_dst, vv);

    // ---- CSR for paper->author ----
    hipMemsetAsync(cnt, 0, NN * sizeof(int), stream);
    k_hist<<<EB, 256, 0, stream>>>(edge_pa + NE, cnt, NE);
    k_scan1<<<NBS, 256, 0, stream>>>(cnt, bsum, NN);
    k_scan2<<<1, 256, 0, stream>>>(bsum, NBS);
    k_scan3<<<NBS, 256, 0, stream>>>(cnt, bsum, rp_pa, NN, NE);
    hipMemcpyAsync(cnt, rp_pa, NN * sizeof(int), hipMemcpyDeviceToDevice, stream);
    k_scatter<<<EB, 256, 0, stream>>>(edge_pa, edge_pa + NE, cnt, col_pa, NE);

    // ---- CSR for author->paper ----
    hipMemsetAsync(cnt, 0, NN * sizeof(int), stream);
    k_hist<<<EB, 256, 0, stream>>>(edge_ap + NE, cnt, NE);
    k_scan1<<<NBS, 256, 0, stream>>>(cnt, bsum, NN);
    k_scan2<<<1, 256, 0, stream>>>(bsum, NBS);
    k_scan3<<<NBS, 256, 0, stream>>>(cnt, bsum, rp_ap, NN, NE);
    hipMemcpyAsync(cnt, rp_ap, NN * sizeof(int), hipMemcpyDeviceToDevice, stream);
    k_scatter<<<EB, 256, 0, stream>>>(edge_ap, edge_ap + NE, cnt, col_ap, NE);

    // ---- GAT layers ----
    const float* xp = x_paper;
    const float* xa = x_author;
    for (int l = 0; l < LL; ++l) {
        int t0 = l * 2 + 0, t1 = l * 2 + 1;
        // a_s0 = xp . vsrc[l,0], a_d1 = xp . vdst[l,1]
        k_dualdot<<<12500, 256, 0, stream>>>(xp, vv + t0 * HH, vv + (4 + t1) * HH, as0, ad1, NN);
        // a_s1 = xa . vsrc[l,1], a_d0 = xa . vdst[l,0]
        k_dualdot<<<12500, 256, 0, stream>>>(xa, vv + t1 * HH, vv + (4 + t0) * HH, as1, ad0, NN);
        k_gemm<<<1563, 256, 0, stream>>>(xp, Wsrc + (size_t)t0 * HH * HH, H0, NN);
        k_gemm<<<1563, 256, 0, stream>>>(xa, Wsrc + (size_t)t1 * HH * HH, H1, NN);
        // edge_pa: src=paper(H0), dst=author -> XA, bias[l,0]
        k_aggregate<<<12500, 256, 0, stream>>>(rp_pa, col_pa, H0, as0, ad0, bias + t0 * HH, XA, NN);
        // edge_ap: src=author(H1), dst=paper -> XP, bias[l,1]
        k_aggregate<<<12500, 256, 0, stream>>>(rp_ap, col_ap, H1, as1, ad1, bias + t1 * HH, XP, NN);
        xp = XP; xa = XA;
    }

    // ---- pooling + final linear ----
    hipMemsetAsync(pooled, 0, 2 * GG * HH * sizeof(unsigned), stream);
    const int PB = (NN + POOL_CHUNK - 1) / POOL_CHUNK;   // 98
    k_pool<<<PB, 128, 0, stream>>>(XP, batch_p, pooled, NN);
    k_pool<<<PB, 128, 0, stream>>>(XA, batch_a, pooled + GG * HH, NN);
    k_final<<<8, 256, 0, stream>>>(pooled, linW, linb, out);
}

// Round 3
// 783.905 us; speedup vs baseline: 1.3273x; 1.3273x over previous
//
#include <hip/hip_runtime.h>

constexpr int NN = 50000;    // nodes per type
constexpr int NE = 600000;   // edges per type
constexpr int HH = 128;      // hidden
constexpr int GG = 64;       // graphs
constexpr int LL = 2;        // layers
constexpr int OC = 16;       // out channels
constexpr float NEG = 0.2f;

// ---------- precompute v = W @ att (8 vectors of 128) ----------
__global__ void k_prevec(const float* __restrict__ Wsrc, const float* __restrict__ Wdst,
                         const float* __restrict__ att_src, const float* __restrict__ att_dst,
                         float* __restrict__ v) {
    int b = blockIdx.x;            // 0..7 : kind = b>>2 (0=src,1=dst), lt = b&3
    int kind = b >> 2, lt = b & 3;
    const float* W   = (kind ? Wdst : Wsrc) + (size_t)lt * HH * HH;
    const float* att = (kind ? att_dst : att_src) + lt * HH;
    __shared__ float sa[HH];
    int t = threadIdx.x;           // 128 threads
    sa[t] = att[t];
    __syncthreads();
    float s = 0.f;
    for (int j = 0; j < HH; ++j) s += W[t * HH + j] * sa[j];
    v[b * HH + t] = s;
}

// ---------- CSR build ----------
__global__ void k_hist(const int* __restrict__ dst, int* __restrict__ cnt, int e) {
    int i = blockIdx.x * blockDim.x + threadIdx.x;
    if (i < e) atomicAdd(&cnt[dst[i]], 1);
}

__global__ void k_scan1(const int* __restrict__ cnt, int* __restrict__ bsum, int n) {
    __shared__ int s[256];
    int i = blockIdx.x * 256 + threadIdx.x;
    s[threadIdx.x] = (i < n) ? cnt[i] : 0;
    __syncthreads();
    for (int off = 128; off > 0; off >>= 1) {
        if (threadIdx.x < off) s[threadIdx.x] += s[threadIdx.x + off];
        __syncthreads();
    }
    if (threadIdx.x == 0) bsum[blockIdx.x] = s[0];
}

__global__ void k_scan2(int* __restrict__ bsum, int nb) {   // one block of 256: exclusive scan in place
    __shared__ int s[256];
    int t = threadIdx.x;
    int v = (t < nb) ? bsum[t] : 0;
    s[t] = v;
    __syncthreads();
    for (int off = 1; off < 256; off <<= 1) {
        int x = (t >= off) ? s[t - off] : 0;
        __syncthreads();
        s[t] += x;
        __syncthreads();
    }
    if (t < nb) bsum[t] = s[t] - v;   // exclusive
}

__global__ void k_scan3(const int* __restrict__ cnt, const int* __restrict__ bsum,
                        int* __restrict__ rowptr, int n, int e) {
    __shared__ int s[256];
    int t = threadIdx.x;
    int i = blockIdx.x * 256 + t;
    int v = (i < n) ? cnt[i] : 0;
    s[t] = v;
    __syncthreads();
    for (int off = 1; off < 256; off <<= 1) {
        int x = (t >= off) ? s[t - off] : 0;
        __syncthreads();
        s[t] += x;
        __syncthreads();
    }
    if (i < n) rowptr[i] = bsum[blockIdx.x] + s[t] - v;
    if (i == n - 1) rowptr[n] = e;
}

__global__ void k_scatter(const int* __restrict__ src, const int* __restrict__ dst,
                          int* __restrict__ cursor, int* __restrict__ col, int e) {
    int i = blockIdx.x * blockDim.x + threadIdx.x;
    if (i < e) {
        int d = dst[i];
        int p = atomicAdd(&cursor[d], 1);
        col[p] = src[i];
    }
}

// ---------- a = X . v1, X . v2 (one wave per node) ----------
__global__ __launch_bounds__(256) void k_dualdot(const float* __restrict__ X,
                                                 const float* __restrict__ v1,
                                                 const float* __restrict__ v2,
                                                 float* __restrict__ o1, float* __restrict__ o2, int n) {
    int wid  = (blockIdx.x * blockDim.x + threadIdx.x) >> 6;
    int lane = threadIdx.x & 63;
    if (wid >= n) return;
    float2 x = *(const float2*)(X + (size_t)wid * HH + lane * 2);
    float2 a = *(const float2*)(v1 + lane * 2);
    float2 b = *(const float2*)(v2 + lane * 2);
    float s1 = x.x * a.x + x.y * a.y;
    float s2 = x.x * b.x + x.y * b.y;
    for (int off = 32; off; off >>= 1) {
        s1 += __shfl_xor(s1, off);
        s2 += __shfl_xor(s2, off);
    }
    if (lane == 0) { o1[wid] = s1; o2[wid] = s2; }
}

// ---------- H = X @ W  (fp32, W staged in LDS in K-halves, X transposed in LDS) ----------
__global__ __launch_bounds__(256) void k_gemm(const float* __restrict__ X, const float* __restrict__ W,
                                              float* __restrict__ Hout, int n) {
    __shared__ float Wl[64 * HH];   // 32 KB: W rows kh..kh+63
    __shared__ float Xt[HH * 32];   // 16 KB: transposed [k][r]
    int t = threadIdx.x;
    int r0 = blockIdx.x * 32;

    // stage X tile transposed (coalesced global read)
    for (int f = t; f < 1024; f += 256) {          // 1024 float4 = 32 rows * 32 f4
        int r = f >> 5, k4 = (f & 31) << 2;
        int gr = r0 + r;
        float4 xv = (gr < n) ? *(const float4*)(X + (size_t)gr * HH + k4)
                             : make_float4(0.f, 0.f, 0.f, 0.f);
        Xt[(k4 + 0) * 32 + r] = xv.x;
        Xt[(k4 + 1) * 32 + r] = xv.y;
        Xt[(k4 + 2) * 32 + r] = xv.z;
        Xt[(k4 + 3) * 32 + r] = xv.w;
    }

    int jj = t & 31, rr = t >> 5;
    int c0 = jj * 4, rbase = rr * 4;
    float acc[4][4] = {};

    for (int kh = 0; kh < HH; kh += 64) {
        // stage W rows [kh, kh+64)
        for (int i = t; i < 64 * HH / 4; i += 256)
            ((float4*)Wl)[i] = ((const float4*)(W + (size_t)kh * HH))[i];
        __syncthreads();
        for (int kk = 0; kk < 64; kk += 4) {
#pragma unroll
            for (int q = 0; q < 4; ++q) {
                const float4 wv = *(const float4*)(Wl + (kk + q) * HH + c0);
                const float4 xv = *(const float4*)(Xt + (kh + kk + q) * 32 + rbase);
                acc[0][0] += xv.x * wv.x; acc[0][1] += xv.x * wv.y; acc[0][2] += xv.x * wv.z; acc[0][3] += xv.x * wv.w;
                acc[1][0] += xv.y * wv.x; acc[1][1] += xv.y * wv.y; acc[1][2] += xv.y * wv.z; acc[1][3] += xv.y * wv.w;
                acc[2][0] += xv.z * wv.x; acc[2][1] += xv.z * wv.y; acc[2][2] += xv.z * wv.z; acc[2][3] += xv.z * wv.w;
                acc[3][0] += xv.w * wv.x; acc[3][1] += xv.w * wv.y; acc[3][2] += xv.w * wv.z; acc[3][3] += xv.w * wv.w;
            }
        }
        __syncthreads();
    }

#pragma unroll
    for (int i = 0; i < 4; ++i) {
        int gr = r0 + rbase + i;
        if (gr < n) {
            float4 o = make_float4(acc[i][0], acc[i][1], acc[i][2], acc[i][3]);
            *(float4*)(Hout + (size_t)gr * HH + c0) = o;
        }
    }
}

// ---------- GAT aggregation: one wave per destination node ----------
__global__ __launch_bounds__(256) void k_aggregate(const int* __restrict__ rowptr, const int* __restrict__ col,
                                                   const float* __restrict__ Hs, const float* __restrict__ a_s,
                                                   const float* __restrict__ a_d, const float* __restrict__ bias,
                                                   float* __restrict__ Xout, int n) {
    int w = (blockIdx.x * blockDim.x + threadIdx.x) >> 6;
    int lane = threadIdx.x & 63;
    if (w >= n) return;
    int base = rowptr[w], end = rowptr[w + 1];
    float add = a_d[w];

    // pass 1: segment max (lanes parallel over edges)
    float m = -1e30f;
    for (int j = base + lane; j < end; j += 64) {
        float sc = a_s[col[j]] + add;
        sc = sc > 0.f ? sc : NEG * sc;
        m = fmaxf(m, sc);
    }
    for (int off = 32; off; off >>= 1) m = fmaxf(m, __shfl_xor(m, off));

    // pass 2: weighted accumulate (lanes parallel over features)
    float den = 0.f;
    float2 acc = {0.f, 0.f};
    for (int j = base; j < end; ++j) {
        int s = col[j];                       // wave-uniform
        float sc = a_s[s] + add;
        sc = sc > 0.f ? sc : NEG * sc;
        float ex = __expf(sc - m);
        den += ex;
        float2 h = *(const float2*)(Hs + (size_t)s * HH + lane * 2);
        acc.x += ex * h.x;
        acc.y += ex * h.y;
    }
    float inv = 1.f / (den + 1e-16f);
    float2 b = *(const float2*)(bias + lane * 2);
    float2 o;
    o.x = fmaxf(acc.x * inv + b.x, 0.f);
    o.y = fmaxf(acc.y * inv + b.y, 0.f);
    *(float2*)(Xout + (size_t)w * HH + lane * 2) = o;
}

// ---------- pooling: segment_max over sorted batch, 8 nodes in flight per block ----------
// block = 256 threads = 8 subgroups x 32 lanes; each subgroup owns 8 consecutive nodes,
// lane holds float4 of features (32*4 = 128). Running max, atomicMax flush at graph change.
constexpr int POOL_CHUNK = 64;                       // nodes per block
__global__ __launch_bounds__(256) void k_pool(const float* __restrict__ XPf, const float* __restrict__ XAf,
                                              const int* __restrict__ batch_p, const int* __restrict__ batch_a,
                                              unsigned* __restrict__ pooled, int n, int blocksPerType) {
    int type = blockIdx.x / blocksPerType;
    int blk  = blockIdx.x % blocksPerType;
    const float* X = type ? XAf : XPf;
    const int* batch = type ? batch_a : batch_p;
    unsigned* pool = pooled + type * GG * HH;

    int sub  = threadIdx.x >> 5;                     // 0..7
    int lane = threadIdx.x & 31;                     // float4 index
    int i0 = blk * POOL_CHUNK + sub * (POOL_CHUNK / 8);
    if (i0 >= n) return;
    int i1 = min(i0 + POOL_CHUNK / 8, n);

    int g = batch[i0];
    float4 m = make_float4(0.f, 0.f, 0.f, 0.f);
    for (int i = i0; i < i1; ++i) {
        int gi = batch[i];
        if (gi != g) {
            unsigned* p = pool + g * HH + lane * 4;
            atomicMax(p + 0, __float_as_uint(m.x));
            atomicMax(p + 1, __float_as_uint(m.y));
            atomicMax(p + 2, __float_as_uint(m.z));
            atomicMax(p + 3, __float_as_uint(m.w));
            m = make_float4(0.f, 0.f, 0.f, 0.f);
            g = gi;
        }
        float4 x = *(const float4*)(X + (size_t)i * HH + lane * 4);
        m.x = fmaxf(m.x, x.x);
        m.y = fmaxf(m.y, x.y);
        m.z = fmaxf(m.z, x.z);
        m.w = fmaxf(m.w, x.w);
    }
    unsigned* p = pool + g * HH + lane * 4;
    atomicMax(p + 0, __float_as_uint(m.x));
    atomicMax(p + 1, __float_as_uint(m.y));
    atomicMax(p + 2, __float_as_uint(m.z));
    atomicMax(p + 3, __float_as_uint(m.w));
}

// ---------- final linear: [2][64][128] @ [128][16] + b ----------
__global__ void k_final(const unsigned* __restrict__ pooled, const float* __restrict__ linW,
                        const float* __restrict__ linb, float* __restrict__ out) {
    int idx = blockIdx.x * blockDim.x + threadIdx.x;
    if (idx >= 2 * GG * OC) return;
    int p = idx >> 10;            // which node type
    int g = (idx >> 4) & 63;
    int o = idx & 15;
    const unsigned* row = pooled + (size_t)(p * GG + g) * HH;
    float s = linb[o];
    for (int k = 0; k < HH; ++k) s += __uint_as_float(row[k]) * linW[k * OC + o];
    out[idx] = s;
}

extern "C" void kernel_launch(void* const* d_in, const int* in_sizes, int n_in,
                              void* d_out, int out_size, void* d_ws, size_t ws_size,
                              hipStream_t stream) {
    const float* x_paper  = (const float*)d_in[0];
    const float* x_author = (const float*)d_in[1];
    const int*   edge_pa  = (const int*)d_in[2];   // [2][E], row0=src(paper), row1=dst(author)
    const int*   edge_ap  = (const int*)d_in[3];
    const int*   batch_p  = (const int*)d_in[4];
    const int*   batch_a  = (const int*)d_in[5];
    const float* Wsrc     = (const float*)d_in[6];
    const float* Wdst     = (const float*)d_in[7];
    const float* att_src  = (const float*)d_in[8];
    const float* att_dst  = (const float*)d_in[9];
    const float* bias     = (const float*)d_in[10];
    const float* linW     = (const float*)d_in[11];
    const float* linb     = (const float*)d_in[12];
    float* out = (float*)d_out;

    size_t off = 0;
    char* base = (char*)d_ws;
    auto alloc = [&](size_t bytes) -> void* {
        void* p = base + off;
        off += (bytes + 255) & ~(size_t)255;
        return p;
    };
    float* H0  = (float*)alloc((size_t)NN * HH * 4);
    float* H1  = (float*)alloc((size_t)NN * HH * 4);
    float* XP  = (float*)alloc((size_t)NN * HH * 4);
    float* XA  = (float*)alloc((size_t)NN * HH * 4);
    float* as0 = (float*)alloc(NN * 4);
    float* ad0 = (float*)alloc(NN * 4);
    float* as1 = (float*)alloc(NN * 4);
    float* ad1 = (float*)alloc(NN * 4);
    float* vv  = (float*)alloc(8 * HH * 4);
    int* rp_pa  = (int*)alloc((NN + 1) * 4);
    int* rp_ap  = (int*)alloc((NN + 1) * 4);
    int* col_pa = (int*)alloc(NE * 4);
    int* col_ap = (int*)alloc(NE * 4);
    int* cnt    = (int*)alloc((NN + 1) * 4);
    int* bsum   = (int*)alloc(1024);
    unsigned* pooled = (unsigned*)alloc(2 * GG * HH * 4);

    const int EB  = (NE + 255) / 256;        // 2344
    const int NBS = (NN + 255) / 256;        // 196

    // ---- precompute attention vectors ----
    k_prevec<<<8, 128, 0, stream>>>(Wsrc, Wdst, att_src, att_dst, vv);

    // ---- CSR for paper->author ----
    hipMemsetAsync(cnt, 0, NN * sizeof(int), stream);
    k_hist<<<EB, 256, 0, stream>>>(edge_pa + NE, cnt, NE);
    k_scan1<<<NBS, 256, 0, stream>>>(cnt, bsum, NN);
    k_scan2<<<1, 256, 0, stream>>>(bsum, NBS);
    k_scan3<<<NBS, 256, 0, stream>>>(cnt, bsum, rp_pa, NN, NE);
    hipMemcpyAsync(cnt, rp_pa, NN * sizeof(int), hipMemcpyDeviceToDevice, stream);
    k_scatter<<<EB, 256, 0, stream>>>(edge_pa, edge_pa + NE, cnt, col_pa, NE);

    // ---- CSR for author->paper ----
    hipMemsetAsync(cnt, 0, NN * sizeof(int), stream);
    k_hist<<<EB, 256, 0, stream>>>(edge_ap + NE, cnt, NE);
    k_scan1<<<NBS, 256, 0, stream>>>(cnt, bsum, NN);
    k_scan2<<<1, 256, 0, stream>>>(bsum, NBS);
    k_scan3<<<NBS, 256, 0, stream>>>(cnt, bsum, rp_ap, NN, NE);
    hipMemcpyAsync(cnt, rp_ap, NN * sizeof(int), hipMemcpyDeviceToDevice, stream);
    k_scatter<<<EB, 256, 0, stream>>>(edge_ap, edge_ap + NE, cnt, col_ap, NE);

    // ---- GAT layers ----
    const float* xp = x_paper;
    const float* xa = x_author;
    for (int l = 0; l < LL; ++l) {
        int t0 = l * 2 + 0, t1 = l * 2 + 1;
        // a_s0 = xp . vsrc[l,0], a_d1 = xp . vdst[l,1]
        k_dualdot<<<12500, 256, 0, stream>>>(xp, vv + t0 * HH, vv + (4 + t1) * HH, as0, ad1, NN);
        // a_s1 = xa . vsrc[l,1], a_d0 = xa . vdst[l,0]
        k_dualdot<<<12500, 256, 0, stream>>>(xa, vv + t1 * HH, vv + (4 + t0) * HH, as1, ad0, NN);
        k_gemm<<<1563, 256, 0, stream>>>(xp, Wsrc + (size_t)t0 * HH * HH, H0, NN);
        k_gemm<<<1563, 256, 0, stream>>>(xa, Wsrc + (size_t)t1 * HH * HH, H1, NN);
        // edge_pa: src=paper(H0), dst=author -> XA, bias[l,0]
        k_aggregate<<<12500, 256, 0, stream>>>(rp_pa, col_pa, H0, as0, ad0, bias + t0 * HH, XA, NN);
        // edge_ap: src=author(H1), dst=paper -> XP, bias[l,1]
        k_aggregate<<<12500, 256, 0, stream>>>(rp_ap, col_ap, H1, as1, ad1, bias + t1 * HH, XP, NN);
        xp = XP; xa = XA;
    }

    // ---- pooling + final linear ----
    hipMemsetAsync(pooled, 0, 2 * GG * HH * sizeof(unsigned), stream);
    const int PB = (NN + POOL_CHUNK - 1) / POOL_CHUNK;   // 782 per type
    k_pool<<<PB * 2, 256, 0, stream>>>(XP, XA, batch_p, batch_a, pooled, NN, PB);
    k_final<<<8, 256, 0, stream>>>(pooled, linW, linb, out);
}

// Round 4
// 619.702 us; speedup vs baseline: 1.6790x; 1.2650x over previous
//
#include <hip/hip_runtime.h>
#include <hip/hip_fp16.h>

constexpr int NN = 50000;    // nodes per type
constexpr int NE = 600000;   // edges per type
constexpr int HH = 128;      // hidden
constexpr int GG = 64;       // graphs
constexpr int LL = 2;        // layers
constexpr int OC = 16;       // out channels
constexpr float NEG = 0.2f;

// ---------- precompute v = W @ att (8 vectors of 128) ----------
__global__ void k_prevec(const float* __restrict__ Wsrc, const float* __restrict__ Wdst,
                         const float* __restrict__ att_src, const float* __restrict__ att_dst,
                         float* __restrict__ v) {
    int b = blockIdx.x;            // 0..7 : kind = b>>2 (0=src,1=dst), lt = b&3
    int kind = b >> 2, lt = b & 3;
    const float* W   = (kind ? Wdst : Wsrc) + (size_t)lt * HH * HH;
    const float* att = (kind ? att_dst : att_src) + lt * HH;
    __shared__ float sa[HH];
    int t = threadIdx.x;           // 128 threads
    sa[t] = att[t];
    __syncthreads();
    float s = 0.f;
    for (int j = 0; j < HH; ++j) s += W[t * HH + j] * sa[j];
    v[b * HH + t] = s;
}

// ---------- CSR build ----------
__global__ void k_hist(const int* __restrict__ dst, int* __restrict__ cnt, int e) {
    int i = blockIdx.x * blockDim.x + threadIdx.x;
    if (i < e) atomicAdd(&cnt[dst[i]], 1);
}

__global__ void k_scan1(const int* __restrict__ cnt, int* __restrict__ bsum, int n) {
    __shared__ int s[256];
    int i = blockIdx.x * 256 + threadIdx.x;
    s[threadIdx.x] = (i < n) ? cnt[i] : 0;
    __syncthreads();
    for (int off = 128; off > 0; off >>= 1) {
        if (threadIdx.x < off) s[threadIdx.x] += s[threadIdx.x + off];
        __syncthreads();
    }
    if (threadIdx.x == 0) bsum[blockIdx.x] = s[0];
}

__global__ void k_scan2(int* __restrict__ bsum, int nb) {   // one block of 256: exclusive scan in place
    __shared__ int s[256];
    int t = threadIdx.x;
    int v = (t < nb) ? bsum[t] : 0;
    s[t] = v;
    __syncthreads();
    for (int off = 1; off < 256; off <<= 1) {
        int x = (t >= off) ? s[t - off] : 0;
        __syncthreads();
        s[t] += x;
        __syncthreads();
    }
    if (t < nb) bsum[t] = s[t] - v;   // exclusive
}

__global__ void k_scan3(const int* __restrict__ cnt, const int* __restrict__ bsum,
                        int* __restrict__ rowptr, int n, int e) {
    __shared__ int s[256];
    int t = threadIdx.x;
    int i = blockIdx.x * 256 + t;
    int v = (i < n) ? cnt[i] : 0;
    s[t] = v;
    __syncthreads();
    for (int off = 1; off < 256; off <<= 1) {
        int x = (t >= off) ? s[t - off] : 0;
        __syncthreads();
        s[t] += x;
        __syncthreads();
    }
    if (i < n) rowptr[i] = bsum[blockIdx.x] + s[t] - v;
    if (i == n - 1) rowptr[n] = e;
}

__global__ void k_scatter(const int* __restrict__ src, const int* __restrict__ dst,
                          int* __restrict__ cursor, int* __restrict__ col, int e) {
    int i = blockIdx.x * blockDim.x + threadIdx.x;
    if (i < e) {
        int d = dst[i];
        int p = atomicAdd(&cursor[d], 1);
        col[p] = src[i];
    }
}

// ---------- a = X . v1, X . v2 (one wave per node) ----------
__global__ __launch_bounds__(256) void k_dualdot(const float* __restrict__ X,
                                                 const float* __restrict__ v1,
                                                 const float* __restrict__ v2,
                                                 float* __restrict__ o1, float* __restrict__ o2, int n) {
    int wid  = (blockIdx.x * blockDim.x + threadIdx.x) >> 6;
    int lane = threadIdx.x & 63;
    if (wid >= n) return;
    float2 x = *(const float2*)(X + (size_t)wid * HH + lane * 2);
    float2 a = *(const float2*)(v1 + lane * 2);
    float2 b = *(const float2*)(v2 + lane * 2);
    float s1 = x.x * a.x + x.y * a.y;
    float s2 = x.x * b.x + x.y * b.y;
    for (int off = 32; off; off >>= 1) {
        s1 += __shfl_xor(s1, off);
        s2 += __shfl_xor(s2, off);
    }
    if (lane == 0) { o1[wid] = s1; o2[wid] = s2; }
}

// ---------- H = X @ W  (fp32 math, fp16 output for cheap gathers) ----------
__global__ __launch_bounds__(256) void k_gemm(const float* __restrict__ X, const float* __restrict__ W,
                                              __half* __restrict__ Hout, int n) {
    __shared__ float Wl[64 * HH];   // 32 KB: W rows kh..kh+63
    __shared__ float Xt[HH * 32];   // 16 KB: transposed [k][r]
    int t = threadIdx.x;
    int r0 = blockIdx.x * 32;

    // stage X tile transposed (coalesced global read)
    for (int f = t; f < 1024; f += 256) {          // 1024 float4 = 32 rows * 32 f4
        int r = f >> 5, k4 = (f & 31) << 2;
        int gr = r0 + r;
        float4 xv = (gr < n) ? *(const float4*)(X + (size_t)gr * HH + k4)
                             : make_float4(0.f, 0.f, 0.f, 0.f);
        Xt[(k4 + 0) * 32 + r] = xv.x;
        Xt[(k4 + 1) * 32 + r] = xv.y;
        Xt[(k4 + 2) * 32 + r] = xv.z;
        Xt[(k4 + 3) * 32 + r] = xv.w;
    }

    int jj = t & 31, rr = t >> 5;
    int c0 = jj * 4, rbase = rr * 4;
    float acc[4][4] = {};

    for (int kh = 0; kh < HH; kh += 64) {
        // stage W rows [kh, kh+64)
        for (int i = t; i < 64 * HH / 4; i += 256)
            ((float4*)Wl)[i] = ((const float4*)(W + (size_t)kh * HH))[i];
        __syncthreads();
        for (int kk = 0; kk < 64; kk += 4) {
#pragma unroll
            for (int q = 0; q < 4; ++q) {
                const float4 wv = *(const float4*)(Wl + (kk + q) * HH + c0);
                const float4 xv = *(const float4*)(Xt + (kh + kk + q) * 32 + rbase);
                acc[0][0] += xv.x * wv.x; acc[0][1] += xv.x * wv.y; acc[0][2] += xv.x * wv.z; acc[0][3] += xv.x * wv.w;
                acc[1][0] += xv.y * wv.x; acc[1][1] += xv.y * wv.y; acc[1][2] += xv.y * wv.z; acc[1][3] += xv.y * wv.w;
                acc[2][0] += xv.z * wv.x; acc[2][1] += xv.z * wv.y; acc[2][2] += xv.z * wv.z; acc[2][3] += xv.z * wv.w;
                acc[3][0] += xv.w * wv.x; acc[3][1] += xv.w * wv.y; acc[3][2] += xv.w * wv.z; acc[3][3] += xv.w * wv.w;
            }
        }
        __syncthreads();
    }

#pragma unroll
    for (int i = 0; i < 4; ++i) {
        int gr = r0 + rbase + i;
        if (gr < n) {
            __half2 ha = __halves2half2(__float2half_rn(acc[i][0]), __float2half_rn(acc[i][1]));
            __half2 hb = __halves2half2(__float2half_rn(acc[i][2]), __float2half_rn(acc[i][3]));
            uint2 pk;
            pk.x = *reinterpret_cast<unsigned*>(&ha);
            pk.y = *reinterpret_cast<unsigned*>(&hb);
            *(uint2*)(Hout + (size_t)gr * HH + c0) = pk;
        }
    }
}

// ---------- GAT aggregation: one wave per destination node ----------
// Scores e = a_s[src]+a_d[dst] are O(0.1) by construction (W,att ~0.05 scale),
// so softmax needs no max-subtraction (shift-invariant; exp can't overflow).
// Hs is fp16 (256B/row gather). 4-edge ILP unroll keeps 4 gathers in flight.
__global__ __launch_bounds__(256) void k_aggregate(const int* __restrict__ rowptr, const int* __restrict__ col,
                                                   const __half* __restrict__ Hs, const float* __restrict__ a_s,
                                                   const float* __restrict__ a_d, const float* __restrict__ bias,
                                                   float* __restrict__ Xout, int n) {
    int w = (blockIdx.x * blockDim.x + threadIdx.x) >> 6;
    int lane = threadIdx.x & 63;
    if (w >= n) return;
    int base = rowptr[w], end = rowptr[w + 1];
    float add = a_d[w];

    float den = 0.f;
    float2 acc = {0.f, 0.f};
    const __half2* H2 = (const __half2*)Hs;

    int j = base;
    for (; j + 4 <= end; j += 4) {
        int s0 = col[j + 0], s1 = col[j + 1], s2 = col[j + 2], s3 = col[j + 3];
        float c0 = a_s[s0] + add, c1 = a_s[s1] + add, c2 = a_s[s2] + add, c3 = a_s[s3] + add;
        __half2 h0 = H2[(size_t)s0 * (HH / 2) + lane];
        __half2 h1 = H2[(size_t)s1 * (HH / 2) + lane];
        __half2 h2 = H2[(size_t)s2 * (HH / 2) + lane];
        __half2 h3 = H2[(size_t)s3 * (HH / 2) + lane];
        c0 = c0 > 0.f ? c0 : NEG * c0;
        c1 = c1 > 0.f ? c1 : NEG * c1;
        c2 = c2 > 0.f ? c2 : NEG * c2;
        c3 = c3 > 0.f ? c3 : NEG * c3;
        float e0 = __expf(c0), e1 = __expf(c1), e2 = __expf(c2), e3 = __expf(c3);
        den += (e0 + e1) + (e2 + e3);
        float2 f0 = __half22float2(h0), f1 = __half22float2(h1);
        float2 f2 = __half22float2(h2), f3 = __half22float2(h3);
        acc.x += e0 * f0.x + e1 * f1.x + e2 * f2.x + e3 * f3.x;
        acc.y += e0 * f0.y + e1 * f1.y + e2 * f2.y + e3 * f3.y;
    }
    for (; j < end; ++j) {
        int s = col[j];
        float c = a_s[s] + add;
        c = c > 0.f ? c : NEG * c;
        float e = __expf(c);
        den += e;
        float2 f = __half22float2(H2[(size_t)s * (HH / 2) + lane]);
        acc.x += e * f.x;
        acc.y += e * f.y;
    }

    float inv = 1.f / (den + 1e-16f);
    float2 b = *(const float2*)(bias + lane * 2);
    float2 o;
    o.x = fmaxf(acc.x * inv + b.x, 0.f);
    o.y = fmaxf(acc.y * inv + b.y, 0.f);
    *(float2*)(Xout + (size_t)w * HH + lane * 2) = o;
}

// ---------- pooling: segment_max over sorted batch, 8 nodes in flight per block ----------
constexpr int POOL_CHUNK = 64;                       // nodes per block
__global__ __launch_bounds__(256) void k_pool(const float* __restrict__ XPf, const float* __restrict__ XAf,
                                              const int* __restrict__ batch_p, const int* __restrict__ batch_a,
                                              unsigned* __restrict__ pooled, int n, int blocksPerType) {
    int type = blockIdx.x / blocksPerType;
    int blk  = blockIdx.x % blocksPerType;
    const float* X = type ? XAf : XPf;
    const int* batch = type ? batch_a : batch_p;
    unsigned* pool = pooled + type * GG * HH;

    int sub  = threadIdx.x >> 5;                     // 0..7
    int lane = threadIdx.x & 31;                     // float4 index
    int i0 = blk * POOL_CHUNK + sub * (POOL_CHUNK / 8);
    if (i0 >= n) return;
    int i1 = min(i0 + POOL_CHUNK / 8, n);

    int g = batch[i0];
    float4 m = make_float4(0.f, 0.f, 0.f, 0.f);
    for (int i = i0; i < i1; ++i) {
        int gi = batch[i];
        if (gi != g) {
            unsigned* p = pool + g * HH + lane * 4;
            atomicMax(p + 0, __float_as_uint(m.x));
            atomicMax(p + 1, __float_as_uint(m.y));
            atomicMax(p + 2, __float_as_uint(m.z));
            atomicMax(p + 3, __float_as_uint(m.w));
            m = make_float4(0.f, 0.f, 0.f, 0.f);
            g = gi;
        }
        float4 x = *(const float4*)(X + (size_t)i * HH + lane * 4);
        m.x = fmaxf(m.x, x.x);
        m.y = fmaxf(m.y, x.y);
        m.z = fmaxf(m.z, x.z);
        m.w = fmaxf(m.w, x.w);
    }
    unsigned* p = pool + g * HH + lane * 4;
    atomicMax(p + 0, __float_as_uint(m.x));
    atomicMax(p + 1, __float_as_uint(m.y));
    atomicMax(p + 2, __float_as_uint(m.z));
    atomicMax(p + 3, __float_as_uint(m.w));
}

// ---------- final linear: [2][64][128] @ [128][16] + b ----------
__global__ void k_final(const unsigned* __restrict__ pooled, const float* __restrict__ linW,
                        const float* __restrict__ linb, float* __restrict__ out) {
    int idx = blockIdx.x * blockDim.x + threadIdx.x;
    if (idx >= 2 * GG * OC) return;
    int p = idx >> 10;            // which node type
    int g = (idx >> 4) & 63;
    int o = idx & 15;
    const unsigned* row = pooled + (size_t)(p * GG + g) * HH;
    float s = linb[o];
    for (int k = 0; k < HH; ++k) s += __uint_as_float(row[k]) * linW[k * OC + o];
    out[idx] = s;
}

extern "C" void kernel_launch(void* const* d_in, const int* in_sizes, int n_in,
                              void* d_out, int out_size, void* d_ws, size_t ws_size,
                              hipStream_t stream) {
    const float* x_paper  = (const float*)d_in[0];
    const float* x_author = (const float*)d_in[1];
    const int*   edge_pa  = (const int*)d_in[2];   // [2][E], row0=src(paper), row1=dst(author)
    const int*   edge_ap  = (const int*)d_in[3];
    const int*   batch_p  = (const int*)d_in[4];
    const int*   batch_a  = (const int*)d_in[5];
    const float* Wsrc     = (const float*)d_in[6];
    const float* Wdst     = (const float*)d_in[7];
    const float* att_src  = (const float*)d_in[8];
    const float* att_dst  = (const float*)d_in[9];
    const float* bias     = (const float*)d_in[10];
    const float* linW     = (const float*)d_in[11];
    const float* linb     = (const float*)d_in[12];
    float* out = (float*)d_out;

    size_t off = 0;
    char* base = (char*)d_ws;
    auto alloc = [&](size_t bytes) -> void* {
        void* p = base + off;
        off += (bytes + 255) & ~(size_t)255;
        return p;
    };
    __half* H0 = (__half*)alloc((size_t)NN * HH * 2);
    __half* H1 = (__half*)alloc((size_t)NN * HH * 2);
    float* XP  = (float*)alloc((size_t)NN * HH * 4);
    float* XA  = (float*)alloc((size_t)NN * HH * 4);
    float* as0 = (float*)alloc(NN * 4);
    float* ad0 = (float*)alloc(NN * 4);
    float* as1 = (float*)alloc(NN * 4);
    float* ad1 = (float*)alloc(NN * 4);
    float* vv  = (float*)alloc(8 * HH * 4);
    int* rp_pa  = (int*)alloc((NN + 1) * 4);
    int* rp_ap  = (int*)alloc((NN + 1) * 4);
    int* col_pa = (int*)alloc(NE * 4);
    int* col_ap = (int*)alloc(NE * 4);
    int* cnt    = (int*)alloc((NN + 1) * 4);
    int* bsum   = (int*)alloc(1024);
    unsigned* pooled = (unsigned*)alloc(2 * GG * HH * 4);

    const int EB  = (NE + 255) / 256;        // 2344
    const int NBS = (NN + 255) / 256;        // 196

    // ---- precompute attention vectors ----
    k_prevec<<<8, 128, 0, stream>>>(Wsrc, Wdst, att_src, att_dst, vv);

    // ---- CSR for paper->author ----
    hipMemsetAsync(cnt, 0, NN * sizeof(int), stream);
    k_hist<<<EB, 256, 0, stream>>>(edge_pa + NE, cnt, NE);
    k_scan1<<<NBS, 256, 0, stream>>>(cnt, bsum, NN);
    k_scan2<<<1, 256, 0, stream>>>(bsum, NBS);
    k_scan3<<<NBS, 256, 0, stream>>>(cnt, bsum, rp_pa, NN, NE);
    hipMemcpyAsync(cnt, rp_pa, NN * sizeof(int), hipMemcpyDeviceToDevice, stream);
    k_scatter<<<EB, 256, 0, stream>>>(edge_pa, edge_pa + NE, cnt, col_pa, NE);

    // ---- CSR for author->paper ----
    hipMemsetAsync(cnt, 0, NN * sizeof(int), stream);
    k_hist<<<EB, 256, 0, stream>>>(edge_ap + NE, cnt, NE);
    k_scan1<<<NBS, 256, 0, stream>>>(cnt, bsum, NN);
    k_scan2<<<1, 256, 0, stream>>>(bsum, NBS);
    k_scan3<<<NBS, 256, 0, stream>>>(cnt, bsum, rp_ap, NN, NE);
    hipMemcpyAsync(cnt, rp_ap, NN * sizeof(int), hipMemcpyDeviceToDevice, stream);
    k_scatter<<<EB, 256, 0, stream>>>(edge_ap, edge_ap + NE, cnt, col_ap, NE);

    // ---- GAT layers ----
    const float* xp = x_paper;
    const float* xa = x_author;
    for (int l = 0; l < LL; ++l) {
        int t0 = l * 2 + 0, t1 = l * 2 + 1;
        // a_s0 = xp . vsrc[l,0], a_d1 = xp . vdst[l,1]
        k_dualdot<<<12500, 256, 0, stream>>>(xp, vv + t0 * HH, vv + (4 + t1) * HH, as0, ad1, NN);
        // a_s1 = xa . vsrc[l,1], a_d0 = xa . vdst[l,0]
        k_dualdot<<<12500, 256, 0, stream>>>(xa, vv + t1 * HH, vv + (4 + t0) * HH, as1, ad0, NN);
        k_gemm<<<1563, 256, 0, stream>>>(xp, Wsrc + (size_t)t0 * HH * HH, H0, NN);
        k_gemm<<<1563, 256, 0, stream>>>(xa, Wsrc + (size_t)t1 * HH * HH, H1, NN);
        // edge_pa: src=paper(H0), dst=author -> XA, bias[l,0]
        k_aggregate<<<12500, 256, 0, stream>>>(rp_pa, col_pa, H0, as0, ad0, bias + t0 * HH, XA, NN);
        // edge_ap: src=author(H1), dst=paper -> XP, bias[l,1]
        k_aggregate<<<12500, 256, 0, stream>>>(rp_ap, col_ap, H1, as1, ad1, bias + t1 * HH, XP, NN);
        xp = XP; xa = XA;
    }

    // ---- pooling + final linear ----
    hipMemsetAsync(pooled, 0, 2 * GG * HH * sizeof(unsigned), stream);
    const int PB = (NN + POOL_CHUNK - 1) / POOL_CHUNK;   // 782 per type
    k_pool<<<PB * 2, 256, 0, stream>>>(XP, XA, batch_p, batch_a, pooled, NN, PB);
    k_final<<<8, 256, 0, stream>>>(pooled, linW, linb, out);
}

// Round 6
// 550.150 us; speedup vs baseline: 1.8912x; 1.1264x over previous
//
#include <hip/hip_runtime.h>
#include <hip/hip_fp16.h>

constexpr int NN = 50000;    // nodes per type
constexpr int NE = 600000;   // edges per type
constexpr int HH = 128;      // hidden
constexpr int GG = 64;       // graphs
constexpr int LL = 2;        // layers
constexpr int OC = 16;       // out channels
constexpr float NEG = 0.2f;

typedef _Float16 f16x8 __attribute__((ext_vector_type(8)));
typedef float f32x4 __attribute__((ext_vector_type(4)));

// ---------- precompute v = W @ att (8 vectors of 128) ----------
__global__ void k_prevec(const float* __restrict__ Wsrc, const float* __restrict__ Wdst,
                         const float* __restrict__ att_src, const float* __restrict__ att_dst,
                         float* __restrict__ v) {
    int b = blockIdx.x;            // 0..7 : kind = b>>2 (0=src,1=dst), lt = b&3
    int kind = b >> 2, lt = b & 3;
    const float* W   = (kind ? Wdst : Wsrc) + (size_t)lt * HH * HH;
    const float* att = (kind ? att_dst : att_src) + lt * HH;
    __shared__ float sa[HH];
    int t = threadIdx.x;           // 128 threads
    sa[t] = att[t];
    __syncthreads();
    float s = 0.f;
    for (int j = 0; j < HH; ++j) s += W[t * HH + j] * sa[j];
    v[b * HH + t] = s;
}

// ---------- W -> transposed fp16 (only Wsrc feeds the GEMMs) ----------
__global__ void k_wcvt(const float* __restrict__ Wsrc, __half* __restrict__ Wt) {
    // Wt[lt][n][k] = Wsrc[lt][k][n]
    int lt = blockIdx.x >> 7;          // 0..3
    int nrow = blockIdx.x & 127;       // output row = original col
    int k = threadIdx.x;               // 128
    Wt[((size_t)lt * HH + nrow) * HH + k] =
        __float2half_rn(Wsrc[(size_t)lt * HH * HH + (size_t)k * HH + nrow]);
}

// ---------- CSR build ----------
__global__ void k_hist(const int* __restrict__ dst, int* __restrict__ cnt, int e) {
    int i = blockIdx.x * blockDim.x + threadIdx.x;
    if (i < e) atomicAdd(&cnt[dst[i]], 1);
}

__global__ void k_scan1(const int* __restrict__ cnt, int* __restrict__ bsum, int n) {
    __shared__ int s[256];
    int i = blockIdx.x * 256 + threadIdx.x;
    s[threadIdx.x] = (i < n) ? cnt[i] : 0;
    __syncthreads();
    for (int off = 128; off > 0; off >>= 1) {
        if (threadIdx.x < off) s[threadIdx.x] += s[threadIdx.x + off];
        __syncthreads();
    }
    if (threadIdx.x == 0) bsum[blockIdx.x] = s[0];
}

__global__ void k_scan2(int* __restrict__ bsum, int nb) {   // one block of 256: exclusive scan in place
    __shared__ int s[256];
    int t = threadIdx.x;
    int v = (t < nb) ? bsum[t] : 0;
    s[t] = v;
    __syncthreads();
    for (int off = 1; off < 256; off <<= 1) {
        int x = (t >= off) ? s[t - off] : 0;
        __syncthreads();
        s[t] += x;
        __syncthreads();
    }
    if (t < nb) bsum[t] = s[t] - v;   // exclusive
}

__global__ void k_scan3(const int* __restrict__ cnt, const int* __restrict__ bsum,
                        int* __restrict__ rowptr, int n, int e) {
    __shared__ int s[256];
    int t = threadIdx.x;
    int i = blockIdx.x * 256 + t;
    int v = (i < n) ? cnt[i] : 0;
    s[t] = v;
    __syncthreads();
    for (int off = 1; off < 256; off <<= 1) {
        int x = (t >= off) ? s[t - off] : 0;
        __syncthreads();
        s[t] += x;
        __syncthreads();
    }
    if (i < n) rowptr[i] = bsum[blockIdx.x] + s[t] - v;
    if (i == n - 1) rowptr[n] = e;
}

__global__ void k_scatter(const int* __restrict__ src, const int* __restrict__ dst,
                          int* __restrict__ cursor, int* __restrict__ col, int e) {
    int i = blockIdx.x * blockDim.x + threadIdx.x;
    if (i < e) {
        int d = dst[i];
        int p = atomicAdd(&cursor[d], 1);
        col[p] = src[i];
    }
}

// ---------- a = X . v1, X . v2 (one wave per node) ----------
__global__ __launch_bounds__(256) void k_dualdot(const float* __restrict__ X,
                                                 const float* __restrict__ v1,
                                                 const float* __restrict__ v2,
                                                 float* __restrict__ o1, float* __restrict__ o2, int n) {
    int wid  = (blockIdx.x * blockDim.x + threadIdx.x) >> 6;
    int lane = threadIdx.x & 63;
    if (wid >= n) return;
    float2 x = *(const float2*)(X + (size_t)wid * HH + lane * 2);
    float2 a = *(const float2*)(v1 + lane * 2);
    float2 b = *(const float2*)(v2 + lane * 2);
    float s1 = x.x * a.x + x.y * a.y;
    float s2 = x.x * b.x + x.y * b.y;
    for (int off = 32; off; off >>= 1) {
        s1 += __shfl_xor(s1, off);
        s2 += __shfl_xor(s2, off);
    }
    if (lane == 0) { o1[wid] = s1; o2[wid] = s2; }
}

// ---------- H = X @ W via MFMA (fp16 inputs, split-A for fp32-exact X) ----------
// Block = 256 threads = 4 waves; wave w owns rows [blk*64 + w*16, +16), all 128 cols.
// A frag: A[lane&15][ (lane>>4)*8 + j ]   (from X, fp32->hi/lo fp16 split)
// B frag: B[(lane>>4)*8 + j][lane&15]     (from Wt[n][k]: 8 contiguous fp16)
// D     : D[(lane>>4)*4 + reg][lane&15]
__global__ __launch_bounds__(256) void k_gemm(const float* __restrict__ X, const __half* __restrict__ Wt,
                                              __half* __restrict__ Hout, int n) {
    int wave = threadIdx.x >> 6;
    int lane = threadIdx.x & 63;
    int r0 = blockIdx.x * 64 + wave * 16;
    int arow = r0 + (lane & 15);
    int kgrp = (lane >> 4) * 8;

    f32x4 acc[8] = {};
#pragma unroll
    for (int ks = 0; ks < 4; ++ks) {
        int k0 = ks * 32 + kgrp;
        float xv[8];
        if (arow < n) {
            float4 x0 = *(const float4*)(X + (size_t)arow * HH + k0);
            float4 x1 = *(const float4*)(X + (size_t)arow * HH + k0 + 4);
            xv[0] = x0.x; xv[1] = x0.y; xv[2] = x0.z; xv[3] = x0.w;
            xv[4] = x1.x; xv[5] = x1.y; xv[6] = x1.z; xv[7] = x1.w;
        } else {
#pragma unroll
            for (int i = 0; i < 8; ++i) xv[i] = 0.f;
        }
        f16x8 ahi, alo;
#pragma unroll
        for (int i = 0; i < 8; ++i) {
            _Float16 h = (_Float16)xv[i];
            ahi[i] = h;
            alo[i] = (_Float16)(xv[i] - (float)h);
        }
#pragma unroll
        for (int nt = 0; nt < 8; ++nt) {
            const f16x8 b = *(const f16x8*)(Wt + ((size_t)(nt * 16 + (lane & 15))) * HH + k0);
            acc[nt] = __builtin_amdgcn_mfma_f32_16x16x32_f16(alo, b, acc[nt], 0, 0, 0);
            acc[nt] = __builtin_amdgcn_mfma_f32_16x16x32_f16(ahi, b, acc[nt], 0, 0, 0);
        }
    }

    int srow = r0 + (lane >> 4) * 4;
    int scol = lane & 15;
#pragma unroll
    for (int nt = 0; nt < 8; ++nt) {
#pragma unroll
        for (int reg = 0; reg < 4; ++reg) {
            int gr = srow + reg;
            if (gr < n) Hout[(size_t)gr * HH + nt * 16 + scol] = __float2half_rn(acc[nt][reg]);
        }
    }
}

// ---------- GAT aggregation: one wave per destination node ----------
// Scores e = a_s[src]+a_d[dst] are O(0.1) by construction, so softmax needs no
// max-subtraction (shift-invariant; exp can't overflow). Hs is fp16. 4-edge ILP.
__global__ __launch_bounds__(256) void k_aggregate(const int* __restrict__ rowptr, const int* __restrict__ col,
                                                   const __half* __restrict__ Hs, const float* __restrict__ a_s,
                                                   const float* __restrict__ a_d, const float* __restrict__ bias,
                                                   float* __restrict__ Xout, int n) {
    int w = (blockIdx.x * blockDim.x + threadIdx.x) >> 6;
    int lane = threadIdx.x & 63;
    if (w >= n) return;
    int base = rowptr[w], end = rowptr[w + 1];
    float add = a_d[w];

    float den = 0.f;
    float2 acc = {0.f, 0.f};
    const __half2* H2 = (const __half2*)Hs;

    int j = base;
    for (; j + 4 <= end; j += 4) {
        int s0 = col[j + 0], s1 = col[j + 1], s2 = col[j + 2], s3 = col[j + 3];
        float c0 = a_s[s0] + add, c1 = a_s[s1] + add, c2 = a_s[s2] + add, c3 = a_s[s3] + add;
        __half2 h0 = H2[(size_t)s0 * (HH / 2) + lane];
        __half2 h1 = H2[(size_t)s1 * (HH / 2) + lane];
        __half2 h2 = H2[(size_t)s2 * (HH / 2) + lane];
        __half2 h3 = H2[(size_t)s3 * (HH / 2) + lane];
        c0 = c0 > 0.f ? c0 : NEG * c0;
        c1 = c1 > 0.f ? c1 : NEG * c1;
        c2 = c2 > 0.f ? c2 : NEG * c2;
        c3 = c3 > 0.f ? c3 : NEG * c3;
        float e0 = __expf(c0), e1 = __expf(c1), e2 = __expf(c2), e3 = __expf(c3);
        den += (e0 + e1) + (e2 + e3);
        float2 f0 = __half22float2(h0), f1 = __half22float2(h1);
        float2 f2 = __half22float2(h2), f3 = __half22float2(h3);
        acc.x += e0 * f0.x + e1 * f1.x + e2 * f2.x + e3 * f3.x;
        acc.y += e0 * f0.y + e1 * f1.y + e2 * f2.y + e3 * f3.y;
    }
    for (; j < end; ++j) {
        int s = col[j];
        float c = a_s[s] + add;
        c = c > 0.f ? c : NEG * c;
        float e = __expf(c);
        den += e;
        float2 f = __half22float2(H2[(size_t)s * (HH / 2) + lane]);
        acc.x += e * f.x;
        acc.y += e * f.y;
    }

    float inv = 1.f / (den + 1e-16f);
    float2 b = *(const float2*)(bias + lane * 2);
    float2 o;
    o.x = fmaxf(acc.x * inv + b.x, 0.f);
    o.y = fmaxf(acc.y * inv + b.y, 0.f);
    *(float2*)(Xout + (size_t)w * HH + lane * 2) = o;
}

// ---------- pooling: segment_max over sorted batch, 8 nodes in flight per block ----------
constexpr int POOL_CHUNK = 64;                       // nodes per block
__global__ __launch_bounds__(256) void k_pool(const float* __restrict__ XPf, const float* __restrict__ XAf,
                                              const int* __restrict__ batch_p, const int* __restrict__ batch_a,
                                              unsigned* __restrict__ pooled, int n, int blocksPerType) {
    int type = blockIdx.x / blocksPerType;
    int blk  = blockIdx.x % blocksPerType;
    const float* X = type ? XAf : XPf;
    const int* batch = type ? batch_a : batch_p;
    unsigned* pool = pooled + type * GG * HH;

    int sub  = threadIdx.x >> 5;                     // 0..7
    int lane = threadIdx.x & 31;                     // float4 index
    int i0 = blk * POOL_CHUNK + sub * (POOL_CHUNK / 8);
    if (i0 >= n) return;
    int i1 = min(i0 + POOL_CHUNK / 8, n);

    int g = batch[i0];
    float4 m = make_float4(0.f, 0.f, 0.f, 0.f);
    for (int i = i0; i < i1; ++i) {
        int gi = batch[i];
        if (gi != g) {
            unsigned* p = pool + g * HH + lane * 4;
            atomicMax(p + 0, __float_as_uint(m.x));
            atomicMax(p + 1, __float_as_uint(m.y));
            atomicMax(p + 2, __float_as_uint(m.z));
            atomicMax(p + 3, __float_as_uint(m.w));
            m = make_float4(0.f, 0.f, 0.f, 0.f);
            g = gi;
        }
        float4 x = *(const float4*)(X + (size_t)i * HH + lane * 4);
        m.x = fmaxf(m.x, x.x);
        m.y = fmaxf(m.y, x.y);
        m.z = fmaxf(m.z, x.z);
        m.w = fmaxf(m.w, x.w);
    }
    unsigned* p = pool + g * HH + lane * 4;
    atomicMax(p + 0, __float_as_uint(m.x));
    atomicMax(p + 1, __float_as_uint(m.y));
    atomicMax(p + 2, __float_as_uint(m.z));
    atomicMax(p + 3, __float_as_uint(m.w));
}

// ---------- final linear: [2][64][128] @ [128][16] + b ----------
__global__ void k_final(const unsigned* __restrict__ pooled, const float* __restrict__ linW,
                        const float* __restrict__ linb, float* __restrict__ out) {
    int idx = blockIdx.x * blockDim.x + threadIdx.x;
    if (idx >= 2 * GG * OC) return;
    int p = idx >> 10;            // which node type
    int g = (idx >> 4) & 63;
    int o = idx & 15;
    const unsigned* row = pooled + (size_t)(p * GG + g) * HH;
    float s = linb[o];
    for (int k = 0; k < HH; ++k) s += __uint_as_float(row[k]) * linW[k * OC + o];
    out[idx] = s;
}

extern "C" void kernel_launch(void* const* d_in, const int* in_sizes, int n_in,
                              void* d_out, int out_size, void* d_ws, size_t ws_size,
                              hipStream_t stream) {
    const float* x_paper  = (const float*)d_in[0];
    const float* x_author = (const float*)d_in[1];
    const int*   edge_pa  = (const int*)d_in[2];   // [2][E], row0=src(paper), row1=dst(author)
    const int*   edge_ap  = (const int*)d_in[3];
    const int*   batch_p  = (const int*)d_in[4];
    const int*   batch_a  = (const int*)d_in[5];
    const float* Wsrc     = (const float*)d_in[6];
    const float* Wdst     = (const float*)d_in[7];
    const float* att_src  = (const float*)d_in[8];
    const float* att_dst  = (const float*)d_in[9];
    const float* bias     = (const float*)d_in[10];
    const float* linW     = (const float*)d_in[11];
    const float* linb     = (const float*)d_in[12];
    float* out = (float*)d_out;

    size_t off = 0;
    char* base = (char*)d_ws;
    auto alloc = [&](size_t bytes) -> void* {
        void* p = base + off;
        off += (bytes + 255) & ~(size_t)255;
        return p;
    };
    __half* H0 = (__half*)alloc((size_t)NN * HH * 2);
    __half* H1 = (__half*)alloc((size_t)NN * HH * 2);
    float* XP  = (float*)alloc((size_t)NN * HH * 4);
    float* XA  = (float*)alloc((size_t)NN * HH * 4);
    float* as0 = (float*)alloc(NN * 4);
    float* ad0 = (float*)alloc(NN * 4);
    float* as1 = (float*)alloc(NN * 4);
    float* ad1 = (float*)alloc(NN * 4);
    float* vv  = (float*)alloc(8 * HH * 4);
    __half* Wt = (__half*)alloc(4 * HH * HH * 2);
    int* rp_pa  = (int*)alloc((NN + 1) * 4);
    int* rp_ap  = (int*)alloc((NN + 1) * 4);
    int* col_pa = (int*)alloc(NE * 4);
    int* col_ap = (int*)alloc(NE * 4);
    int* cnt    = (int*)alloc((NN + 1) * 4);
    int* bsum   = (int*)alloc(1024);
    unsigned* pooled = (unsigned*)alloc(2 * GG * HH * 4);

    const int EB  = (NE + 255) / 256;        // 2344
    const int NBS = (NN + 255) / 256;        // 196

    // ---- precompute attention vectors + fp16 transposed W ----
    k_prevec<<<8, 128, 0, stream>>>(Wsrc, Wdst, att_src, att_dst, vv);
    k_wcvt<<<512, 128, 0, stream>>>(Wsrc, Wt);

    // ---- CSR for paper->author ----
    hipMemsetAsync(cnt, 0, NN * sizeof(int), stream);
    k_hist<<<EB, 256, 0, stream>>>(edge_pa + NE, cnt, NE);
    k_scan1<<<NBS, 256, 0, stream>>>(cnt, bsum, NN);
    k_scan2<<<1, 256, 0, stream>>>(bsum, NBS);
    k_scan3<<<NBS, 256, 0, stream>>>(cnt, bsum, rp_pa, NN, NE);
    hipMemcpyAsync(cnt, rp_pa, NN * sizeof(int), hipMemcpyDeviceToDevice, stream);
    k_scatter<<<EB, 256, 0, stream>>>(edge_pa, edge_pa + NE, cnt, col_pa, NE);

    // ---- CSR for author->paper ----
    hipMemsetAsync(cnt, 0, NN * sizeof(int), stream);
    k_hist<<<EB, 256, 0, stream>>>(edge_ap + NE, cnt, NE);
    k_scan1<<<NBS, 256, 0, stream>>>(cnt, bsum, NN);
    k_scan2<<<1, 256, 0, stream>>>(bsum, NBS);
    k_scan3<<<NBS, 256, 0, stream>>>(cnt, bsum, rp_ap, NN, NE);
    hipMemcpyAsync(cnt, rp_ap, NN * sizeof(int), hipMemcpyDeviceToDevice, stream);
    k_scatter<<<EB, 256, 0, stream>>>(edge_ap, edge_ap + NE, cnt, col_ap, NE);

    // ---- GAT layers ----
    const float* xp = x_paper;
    const float* xa = x_author;
    const int GB = (NN + 63) / 64;           // 782
    for (int l = 0; l < LL; ++l) {
        int t0 = l * 2 + 0, t1 = l * 2 + 1;
        // a_s0 = xp . vsrc[l,0], a_d1 = xp . vdst[l,1]
        k_dualdot<<<12500, 256, 0, stream>>>(xp, vv + t0 * HH, vv + (4 + t1) * HH, as0, ad1, NN);
        // a_s1 = xa . vsrc[l,1], a_d0 = xa . vdst[l,0]
        k_dualdot<<<12500, 256, 0, stream>>>(xa, vv + t1 * HH, vv + (4 + t0) * HH, as1, ad0, NN);
        k_gemm<<<GB, 256, 0, stream>>>(xp, Wt + (size_t)t0 * HH * HH, H0, NN);
        k_gemm<<<GB, 256, 0, stream>>>(xa, Wt + (size_t)t1 * HH * HH, H1, NN);
        // edge_pa: src=paper(H0), dst=author -> XA, bias[l,0]
        k_aggregate<<<12500, 256, 0, stream>>>(rp_pa, col_pa, H0, as0, ad0, bias + t0 * HH, XA, NN);
        // edge_ap: src=author(H1), dst=paper -> XP, bias[l,1]
        k_aggregate<<<12500, 256, 0, stream>>>(rp_ap, col_ap, H1, as1, ad1, bias + t1 * HH, XP, NN);
        xp = XP; xa = XA;
    }

    // ---- pooling + final linear ----
    hipMemsetAsync(pooled, 0, 2 * GG * HH * sizeof(unsigned), stream);
    const int PB = (NN + POOL_CHUNK - 1) / POOL_CHUNK;   // 782 per type
    k_pool<<<PB * 2, 256, 0, stream>>>(XP, XA, batch_p, batch_a, pooled, NN, PB);
    k_final<<<8, 256, 0, stream>>>(pooled, linW, linb, out);
}

// Round 7
// 524.394 us; speedup vs baseline: 1.9841x; 1.0491x over previous
//
#include <hip/hip_runtime.h>
#include <hip/hip_fp16.h>

constexpr int NN = 50000;    // nodes per type
constexpr int NE = 600000;   // edges per type
constexpr int HH = 128;      // hidden
constexpr int GG = 64;       // graphs
constexpr int LL = 2;        // layers
constexpr int OC = 16;       // out channels
constexpr float NEG = 0.2f;

typedef _Float16 f16x8 __attribute__((ext_vector_type(8)));
typedef float f32x4 __attribute__((ext_vector_type(4)));

// ---------- precompute v = W @ att (8 vectors of 128) ----------
__global__ void k_prevec(const float* __restrict__ Wsrc, const float* __restrict__ Wdst,
                         const float* __restrict__ att_src, const float* __restrict__ att_dst,
                         float* __restrict__ v) {
    int b = blockIdx.x;            // 0..7 : kind = b>>2 (0=src,1=dst), lt = b&3
    int kind = b >> 2, lt = b & 3;
    const float* W   = (kind ? Wdst : Wsrc) + (size_t)lt * HH * HH;
    const float* att = (kind ? att_dst : att_src) + lt * HH;
    __shared__ float sa[HH];
    int t = threadIdx.x;           // 128 threads
    sa[t] = att[t];
    __syncthreads();
    float s = 0.f;
    for (int j = 0; j < HH; ++j) s += W[t * HH + j] * sa[j];
    v[b * HH + t] = s;
}

// ---------- W -> transposed fp16 (only Wsrc feeds the GEMMs) ----------
__global__ void k_wcvt(const float* __restrict__ Wsrc, __half* __restrict__ Wt) {
    // Wt[lt][n][k] = Wsrc[lt][k][n]
    int lt = blockIdx.x >> 7;          // 0..3
    int nrow = blockIdx.x & 127;       // output row = original col
    int k = threadIdx.x;               // 128
    Wt[((size_t)lt * HH + nrow) * HH + k] =
        __float2half_rn(Wsrc[(size_t)lt * HH * HH + (size_t)k * HH + nrow]);
}

// ---------- CSR build (both edge types combined: cnt/rowptr over 2*NN, col over 2*NE) ----------
__global__ void k_hist2(const int* __restrict__ dpa, const int* __restrict__ dap,
                        int* __restrict__ cnt) {
    int i = blockIdx.x * 256 + threadIdx.x;
    if (i < NE) atomicAdd(&cnt[dpa[i]], 1);
    else if (i < 2 * NE) atomicAdd(&cnt[NN + dap[i - NE]], 1);
}

__global__ void k_scan1(const int* __restrict__ cnt, int* __restrict__ bsum, int n) {
    __shared__ int s[256];
    int i = blockIdx.x * 256 + threadIdx.x;
    s[threadIdx.x] = (i < n) ? cnt[i] : 0;
    __syncthreads();
    for (int off = 128; off > 0; off >>= 1) {
        if (threadIdx.x < off) s[threadIdx.x] += s[threadIdx.x + off];
        __syncthreads();
    }
    if (threadIdx.x == 0) bsum[blockIdx.x] = s[0];
}

__global__ void k_scan2(int* __restrict__ bsum, int nb) {   // one block of 512: exclusive scan in place
    __shared__ int s[512];
    int t = threadIdx.x;
    int v = (t < nb) ? bsum[t] : 0;
    s[t] = v;
    __syncthreads();
    for (int off = 1; off < 512; off <<= 1) {
        int x = (t >= off) ? s[t - off] : 0;
        __syncthreads();
        s[t] += x;
        __syncthreads();
    }
    if (t < nb) bsum[t] = s[t] - v;   // exclusive
}

__global__ void k_scan3(const int* __restrict__ cnt, const int* __restrict__ bsum,
                        int* __restrict__ rowptr, int n, int e) {
    __shared__ int s[256];
    int t = threadIdx.x;
    int i = blockIdx.x * 256 + t;
    int v = (i < n) ? cnt[i] : 0;
    s[t] = v;
    __syncthreads();
    for (int off = 1; off < 256; off <<= 1) {
        int x = (t >= off) ? s[t - off] : 0;
        __syncthreads();
        s[t] += x;
        __syncthreads();
    }
    if (i < n) rowptr[i] = bsum[blockIdx.x] + s[t] - v;
    if (i == n - 1) rowptr[n] = e;
}

__global__ void k_scatter2(const int* __restrict__ edge_pa, const int* __restrict__ edge_ap,
                           int* __restrict__ cursor, int* __restrict__ col) {
    int i = blockIdx.x * 256 + threadIdx.x;
    if (i < NE) {
        int d = edge_pa[NE + i];
        int p = atomicAdd(&cursor[d], 1);
        col[p] = edge_pa[i];
    } else if (i < 2 * NE) {
        int j = i - NE;
        int d = edge_ap[NE + j];
        int p = atomicAdd(&cursor[NN + d], 1);
        col[p] = edge_ap[j];
    }
}

// ---------- H = X @ W via MFMA (split-A for fp32-exact X) + fused dual dot ----------
// Block = 256 threads = 4 waves; wave w owns rows [blk*64 + w*16, +16), all 128 cols.
// A frag: A[lane&15][ (lane>>4)*8 + j ] ; B frag: B[(lane>>4)*8 + j][lane&15]
// D: D[(lane>>4)*4 + reg][lane&15]. Also computes o1=X.v1, o2=X.v2 (a_s / a_d for GAT)
// using the X fragments already in registers (4 lanes per row -> shfl_xor 16,32 reduce).
__global__ __launch_bounds__(256) void k_gemm(const float* __restrict__ X, const __half* __restrict__ Wt,
                                              const float* __restrict__ v1, const float* __restrict__ v2,
                                              __half* __restrict__ Hout,
                                              float* __restrict__ o1, float* __restrict__ o2, int n) {
    int wave = threadIdx.x >> 6;
    int lane = threadIdx.x & 63;
    int r0 = blockIdx.x * 64 + wave * 16;
    int arow = r0 + (lane & 15);
    int kgrp = (lane >> 4) * 8;

    f32x4 acc[8] = {};
    float s1 = 0.f, s2 = 0.f;
#pragma unroll
    for (int ks = 0; ks < 4; ++ks) {
        int k0 = ks * 32 + kgrp;
        float xv[8];
        if (arow < n) {
            float4 x0 = *(const float4*)(X + (size_t)arow * HH + k0);
            float4 x1 = *(const float4*)(X + (size_t)arow * HH + k0 + 4);
            xv[0] = x0.x; xv[1] = x0.y; xv[2] = x0.z; xv[3] = x0.w;
            xv[4] = x1.x; xv[5] = x1.y; xv[6] = x1.z; xv[7] = x1.w;
        } else {
#pragma unroll
            for (int i = 0; i < 8; ++i) xv[i] = 0.f;
        }
        // fused attention dots (v1/v2 are L1-resident 512B vectors)
        float4 va0 = *(const float4*)(v1 + k0), va1 = *(const float4*)(v1 + k0 + 4);
        float4 vb0 = *(const float4*)(v2 + k0), vb1 = *(const float4*)(v2 + k0 + 4);
        s1 += xv[0] * va0.x + xv[1] * va0.y + xv[2] * va0.z + xv[3] * va0.w
            + xv[4] * va1.x + xv[5] * va1.y + xv[6] * va1.z + xv[7] * va1.w;
        s2 += xv[0] * vb0.x + xv[1] * vb0.y + xv[2] * vb0.z + xv[3] * vb0.w
            + xv[4] * vb1.x + xv[5] * vb1.y + xv[6] * vb1.z + xv[7] * vb1.w;

        f16x8 ahi, alo;
#pragma unroll
        for (int i = 0; i < 8; ++i) {
            _Float16 h = (_Float16)xv[i];
            ahi[i] = h;
            alo[i] = (_Float16)(xv[i] - (float)h);
        }
#pragma unroll
        for (int nt = 0; nt < 8; ++nt) {
            const f16x8 b = *(const f16x8*)(Wt + ((size_t)(nt * 16 + (lane & 15))) * HH + k0);
            acc[nt] = __builtin_amdgcn_mfma_f32_16x16x32_f16(alo, b, acc[nt], 0, 0, 0);
            acc[nt] = __builtin_amdgcn_mfma_f32_16x16x32_f16(ahi, b, acc[nt], 0, 0, 0);
        }
    }

    // reduce dots across the 4 lanes sharing this row (lane ^ 16, ^ 32)
    s1 += __shfl_xor(s1, 16); s1 += __shfl_xor(s1, 32);
    s2 += __shfl_xor(s2, 16); s2 += __shfl_xor(s2, 32);
    if ((lane >> 4) == 0 && arow < n) { o1[arow] = s1; o2[arow] = s2; }

    int srow = r0 + (lane >> 4) * 4;
    int scol = lane & 15;
#pragma unroll
    for (int nt = 0; nt < 8; ++nt) {
#pragma unroll
        for (int reg = 0; reg < 4; ++reg) {
            int gr = srow + reg;
            if (gr < n) Hout[(size_t)gr * HH + nt * 16 + scol] = __float2half_rn(acc[nt][reg]);
        }
    }
}

// ---------- GAT aggregation, both edge types in one dispatch ----------
// waves [0,NN) -> pa edges (dst=author, out XA); waves [NN,2NN) -> ap edges (out XP).
// Scores are O(0.1) by construction -> no max-subtraction needed (shift-invariant).
__global__ __launch_bounds__(256) void k_aggregate2(const int* __restrict__ rpc, const int* __restrict__ colc,
                                                    const __half* __restrict__ H0, const __half* __restrict__ H1,
                                                    const float* __restrict__ as0, const float* __restrict__ ad0,
                                                    const float* __restrict__ as1, const float* __restrict__ ad1,
                                                    const float* __restrict__ bias0, const float* __restrict__ bias1,
                                                    float* __restrict__ XA, float* __restrict__ XP) {
    int w = (blockIdx.x * blockDim.x + threadIdx.x) >> 6;   // 0..2*NN-1
    int lane = threadIdx.x & 63;
    int type = (w >= NN);
    int node = type ? w - NN : w;
    const int* rowptr = rpc + (type ? NN : 0);
    const __half2* H2  = (const __half2*)(type ? H1 : H0);
    const float* a_s  = type ? as1 : as0;
    float add         = (type ? ad1 : ad0)[node];
    const float* bias = type ? bias1 : bias0;
    float* Xout       = type ? XP : XA;

    int base = rowptr[node], end = rowptr[node + 1];

    float den = 0.f;
    float2 acc = {0.f, 0.f};

    int j = base;
    for (; j + 4 <= end; j += 4) {
        int s0 = colc[j + 0], s1 = colc[j + 1], s2 = colc[j + 2], s3 = colc[j + 3];
        float c0 = a_s[s0] + add, c1 = a_s[s1] + add, c2 = a_s[s2] + add, c3 = a_s[s3] + add;
        __half2 h0 = H2[(size_t)s0 * (HH / 2) + lane];
        __half2 h1 = H2[(size_t)s1 * (HH / 2) + lane];
        __half2 h2 = H2[(size_t)s2 * (HH / 2) + lane];
        __half2 h3 = H2[(size_t)s3 * (HH / 2) + lane];
        c0 = c0 > 0.f ? c0 : NEG * c0;
        c1 = c1 > 0.f ? c1 : NEG * c1;
        c2 = c2 > 0.f ? c2 : NEG * c2;
        c3 = c3 > 0.f ? c3 : NEG * c3;
        float e0 = __expf(c0), e1 = __expf(c1), e2 = __expf(c2), e3 = __expf(c3);
        den += (e0 + e1) + (e2 + e3);
        float2 f0 = __half22float2(h0), f1 = __half22float2(h1);
        float2 f2 = __half22float2(h2), f3 = __half22float2(h3);
        acc.x += e0 * f0.x + e1 * f1.x + e2 * f2.x + e3 * f3.x;
        acc.y += e0 * f0.y + e1 * f1.y + e2 * f2.y + e3 * f3.y;
    }
    for (; j < end; ++j) {
        int s = colc[j];
        float c = a_s[s] + add;
        c = c > 0.f ? c : NEG * c;
        float e = __expf(c);
        den += e;
        float2 f = __half22float2(H2[(size_t)s * (HH / 2) + lane]);
        acc.x += e * f.x;
        acc.y += e * f.y;
    }

    float inv = 1.f / (den + 1e-16f);
    float2 b = *(const float2*)(bias + lane * 2);
    float2 o;
    o.x = fmaxf(acc.x * inv + b.x, 0.f);
    o.y = fmaxf(acc.y * inv + b.y, 0.f);
    *(float2*)(Xout + (size_t)node * HH + lane * 2) = o;
}

// ---------- pooling: segment_max over sorted batch, 8 nodes in flight per block ----------
constexpr int POOL_CHUNK = 64;                       // nodes per block
__global__ __launch_bounds__(256) void k_pool(const float* __restrict__ XPf, const float* __restrict__ XAf,
                                              const int* __restrict__ batch_p, const int* __restrict__ batch_a,
                                              unsigned* __restrict__ pooled, int n, int blocksPerType) {
    int type = blockIdx.x / blocksPerType;
    int blk  = blockIdx.x % blocksPerType;
    const float* X = type ? XAf : XPf;
    const int* batch = type ? batch_a : batch_p;
    unsigned* pool = pooled + type * GG * HH;

    int sub  = threadIdx.x >> 5;                     // 0..7
    int lane = threadIdx.x & 31;                     // float4 index
    int i0 = blk * POOL_CHUNK + sub * (POOL_CHUNK / 8);
    if (i0 >= n) return;
    int i1 = min(i0 + POOL_CHUNK / 8, n);

    int g = batch[i0];
    float4 m = make_float4(0.f, 0.f, 0.f, 0.f);
    for (int i = i0; i < i1; ++i) {
        int gi = batch[i];
        if (gi != g) {
            unsigned* p = pool + g * HH + lane * 4;
            atomicMax(p + 0, __float_as_uint(m.x));
            atomicMax(p + 1, __float_as_uint(m.y));
            atomicMax(p + 2, __float_as_uint(m.z));
            atomicMax(p + 3, __float_as_uint(m.w));
            m = make_float4(0.f, 0.f, 0.f, 0.f);
            g = gi;
        }
        float4 x = *(const float4*)(X + (size_t)i * HH + lane * 4);
        m.x = fmaxf(m.x, x.x);
        m.y = fmaxf(m.y, x.y);
        m.z = fmaxf(m.z, x.z);
        m.w = fmaxf(m.w, x.w);
    }
    unsigned* p = pool + g * HH + lane * 4;
    atomicMax(p + 0, __float_as_uint(m.x));
    atomicMax(p + 1, __float_as_uint(m.y));
    atomicMax(p + 2, __float_as_uint(m.z));
    atomicMax(p + 3, __float_as_uint(m.w));
}

// ---------- final linear: [2][64][128] @ [128][16] + b ----------
__global__ void k_final(const unsigned* __restrict__ pooled, const float* __restrict__ linW,
                        const float* __restrict__ linb, float* __restrict__ out) {
    int idx = blockIdx.x * blockDim.x + threadIdx.x;
    if (idx >= 2 * GG * OC) return;
    int p = idx >> 10;            // which node type
    int g = (idx >> 4) & 63;
    int o = idx & 15;
    const unsigned* row = pooled + (size_t)(p * GG + g) * HH;
    float s = linb[o];
    for (int k = 0; k < HH; ++k) s += __uint_as_float(row[k]) * linW[k * OC + o];
    out[idx] = s;
}

extern "C" void kernel_launch(void* const* d_in, const int* in_sizes, int n_in,
                              void* d_out, int out_size, void* d_ws, size_t ws_size,
                              hipStream_t stream) {
    const float* x_paper  = (const float*)d_in[0];
    const float* x_author = (const float*)d_in[1];
    const int*   edge_pa  = (const int*)d_in[2];   // [2][E], row0=src(paper), row1=dst(author)
    const int*   edge_ap  = (const int*)d_in[3];
    const int*   batch_p  = (const int*)d_in[4];
    const int*   batch_a  = (const int*)d_in[5];
    const float* Wsrc     = (const float*)d_in[6];
    const float* Wdst     = (const float*)d_in[7];
    const float* att_src  = (const float*)d_in[8];
    const float* att_dst  = (const float*)d_in[9];
    const float* bias     = (const float*)d_in[10];
    const float* linW     = (const float*)d_in[11];
    const float* linb     = (const float*)d_in[12];
    float* out = (float*)d_out;

    size_t off = 0;
    char* base = (char*)d_ws;
    auto alloc = [&](size_t bytes) -> void* {
        void* p = base + off;
        off += (bytes + 255) & ~(size_t)255;
        return p;
    };
    __half* H0 = (__half*)alloc((size_t)NN * HH * 2);
    __half* H1 = (__half*)alloc((size_t)NN * HH * 2);
    float* XP  = (float*)alloc((size_t)NN * HH * 4);
    float* XA  = (float*)alloc((size_t)NN * HH * 4);
    float* as0 = (float*)alloc(NN * 4);
    float* ad0 = (float*)alloc(NN * 4);
    float* as1 = (float*)alloc(NN * 4);
    float* ad1 = (float*)alloc(NN * 4);
    float* vv  = (float*)alloc(8 * HH * 4);
    __half* Wt = (__half*)alloc(4 * HH * HH * 2);
    int* rpc  = (int*)alloc((2 * NN + 1) * 4);      // combined rowptr, ap offsets include +NE
    int* colc = (int*)alloc(2 * NE * 4);            // combined col
    int* cnt  = (int*)alloc(2 * NN * 4);
    int* bsum = (int*)alloc(2048);
    unsigned* pooled = (unsigned*)alloc(2 * GG * HH * 4);

    const int EB2  = (2 * NE + 255) / 256;   // 4688
    const int NBS2 = (2 * NN + 255) / 256;   // 391

    // ---- precompute attention vectors + fp16 transposed W ----
    k_prevec<<<8, 128, 0, stream>>>(Wsrc, Wdst, att_src, att_dst, vv);
    k_wcvt<<<512, 128, 0, stream>>>(Wsrc, Wt);

    // ---- combined CSR build for both edge types ----
    hipMemsetAsync(cnt, 0, 2 * NN * sizeof(int), stream);
    k_hist2<<<EB2, 256, 0, stream>>>(edge_pa + NE, edge_ap + NE, cnt);
    k_scan1<<<NBS2, 256, 0, stream>>>(cnt, bsum, 2 * NN);
    k_scan2<<<1, 512, 0, stream>>>(bsum, NBS2);
    k_scan3<<<NBS2, 256, 0, stream>>>(cnt, bsum, rpc, 2 * NN, 2 * NE);
    hipMemcpyAsync(cnt, rpc, 2 * NN * sizeof(int), hipMemcpyDeviceToDevice, stream);
    k_scatter2<<<EB2, 256, 0, stream>>>(edge_pa, edge_ap, cnt, colc);

    // ---- GAT layers ----
    const float* xp = x_paper;
    const float* xa = x_author;
    const int GB = (NN + 63) / 64;           // 782
    for (int l = 0; l < LL; ++l) {
        int t0 = l * 2 + 0, t1 = l * 2 + 1;
        // gemm H0 = xp @ Wsrc[l,0]; fused: as0 = xp.vsrc[t0], ad1 = xp.vdst[t1]
        k_gemm<<<GB, 256, 0, stream>>>(xp, Wt + (size_t)t0 * HH * HH,
                                       vv + t0 * HH, vv + (4 + t1) * HH, H0, as0, ad1, NN);
        // gemm H1 = xa @ Wsrc[l,1]; fused: as1 = xa.vsrc[t1], ad0 = xa.vdst[t0]
        k_gemm<<<GB, 256, 0, stream>>>(xa, Wt + (size_t)t1 * HH * HH,
                                       vv + t1 * HH, vv + (4 + t0) * HH, H1, as1, ad0, NN);
        // both aggregates in one dispatch: pa -> XA (bias[l,0]), ap -> XP (bias[l,1])
        k_aggregate2<<<25000, 256, 0, stream>>>(rpc, colc, H0, H1, as0, ad0, as1, ad1,
                                                bias + t0 * HH, bias + t1 * HH, XA, XP);
        xp = XP; xa = XA;
    }

    // ---- pooling + final linear ----
    hipMemsetAsync(pooled, 0, 2 * GG * HH * sizeof(unsigned), stream);
    const int PB = (NN + POOL_CHUNK - 1) / POOL_CHUNK;   // 782 per type
    k_pool<<<PB * 2, 256, 0, stream>>>(XP, XA, batch_p, batch_a, pooled, NN, PB);
    k_final<<<8, 256, 0, stream>>>(pooled, linW, linb, out);
}

// Round 9
// 450.810 us; speedup vs baseline: 2.3080x; 1.1632x over previous
//
#include <hip/hip_runtime.h>
#include <hip/hip_fp16.h>

constexpr int NN = 50000;    // nodes per type
constexpr int NE = 600000;   // edges per type
constexpr int HH = 128;      // hidden
constexpr int GG = 64;       // graphs
constexpr int LL = 2;        // layers
constexpr int OC = 16;       // out channels
constexpr float NEG = 0.2f;
constexpr int NBK = (2 * NN + 255) / 256;   // 391 destination buckets of 256 nodes

typedef _Float16 f16x8 __attribute__((ext_vector_type(8)));
typedef float f32x4 __attribute__((ext_vector_type(4)));

// ---------- precompute v = W @ att (8 vectors of 128) ----------
__global__ void k_prevec(const float* __restrict__ Wsrc, const float* __restrict__ Wdst,
                         const float* __restrict__ att_src, const float* __restrict__ att_dst,
                         float* __restrict__ v) {
    int b = blockIdx.x;            // 0..7 : kind = b>>2 (0=src,1=dst), lt = b&3
    int kind = b >> 2, lt = b & 3;
    const float* W   = (kind ? Wdst : Wsrc) + (size_t)lt * HH * HH;
    const float* att = (kind ? att_dst : att_src) + lt * HH;
    __shared__ float sa[HH];
    int t = threadIdx.x;           // 128 threads
    sa[t] = att[t];
    __syncthreads();
    float s = 0.f;
    for (int j = 0; j < HH; ++j) s += W[t * HH + j] * sa[j];
    v[b * HH + t] = s;
}

// ---------- W -> transposed fp16 (only Wsrc feeds the GEMMs) ----------
__global__ void k_wcvt(const float* __restrict__ Wsrc, __half* __restrict__ Wt) {
    int lt = blockIdx.x >> 7;          // 0..3
    int nrow = blockIdx.x & 127;       // output row = original col
    int k = threadIdx.x;               // 128
    Wt[((size_t)lt * HH + nrow) * HH + k] =
        __float2half_rn(Wsrc[(size_t)lt * HH * HH + (size_t)k * HH + nrow]);
}

// ---------- CSR build (combined node space: pa-dst in [0,NN), ap-dst in [NN,2NN)) ----------
__global__ void k_hist2(const int* __restrict__ dpa, const int* __restrict__ dap,
                        int* __restrict__ cnt) {
    int i = blockIdx.x * 256 + threadIdx.x;
    if (i < NE) atomicAdd(&cnt[dpa[i]], 1);
    else if (i < 2 * NE) atomicAdd(&cnt[NN + dap[i - NE]], 1);
}

__global__ void k_scan1(const int* __restrict__ cnt, int* __restrict__ bsum, int n) {
    __shared__ int s[256];
    int i = blockIdx.x * 256 + threadIdx.x;
    s[threadIdx.x] = (i < n) ? cnt[i] : 0;
    __syncthreads();
    for (int off = 128; off > 0; off >>= 1) {
        if (threadIdx.x < off) s[threadIdx.x] += s[threadIdx.x + off];
        __syncthreads();
    }
    if (threadIdx.x == 0) bsum[blockIdx.x] = s[0];
}

__global__ void k_scan2(int* __restrict__ bsum, int nb) {   // one block of 512: exclusive scan in place
    __shared__ int s[512];
    int t = threadIdx.x;
    int v = (t < nb) ? bsum[t] : 0;
    s[t] = v;
    __syncthreads();
    for (int off = 1; off < 512; off <<= 1) {
        int x = (t >= off) ? s[t - off] : 0;
        __syncthreads();
        s[t] += x;
        __syncthreads();
    }
    if (t < nb) bsum[t] = s[t] - v;   // exclusive
}

__global__ void k_scan3(const int* __restrict__ cnt, const int* __restrict__ bsum,
                        int* __restrict__ rowptr, int n, int e) {
    __shared__ int s[256];
    int t = threadIdx.x;
    int i = blockIdx.x * 256 + t;
    int v = (i < n) ? cnt[i] : 0;
    s[t] = v;
    __syncthreads();
    for (int off = 1; off < 256; off <<= 1) {
        int x = (t >= off) ? s[t - off] : 0;
        __syncthreads();
        s[t] += x;
        __syncthreads();
    }
    if (i < n) rowptr[i] = bsum[blockIdx.x] + s[t] - v;
    if (i == n - 1) rowptr[n] = e;
}

// bucket cursors start at the bucket's col-region base (free from rowptr)
__global__ void k_binit(const int* __restrict__ rpc, int* __restrict__ bcur) {
    int b = blockIdx.x * 256 + threadIdx.x;
    if (b < NBK) bcur[b] = rpc[b * 256];
}

// Pass 1: bucket-clustered placement of packed (src<<8 | d&255) into colt.
// Per 4096-edge block: LDS bucket counts -> one global atomic per bucket to
// reserve a contiguous run -> place. Same-bucket items land contiguously,
// cutting random-4B-store line waste ~10x vs direct scatter.
__global__ __launch_bounds__(256) void k_bucket1(const int* __restrict__ edge_pa,
                                                 const int* __restrict__ edge_ap,
                                                 int* __restrict__ bcur, unsigned* __restrict__ colt) {
    __shared__ int cnt[NBK];
    __shared__ int gpos[NBK];
    int t = threadIdx.x;
    int e0 = blockIdx.x * 4096;
    int m = min(4096, 2 * NE - e0);
    for (int i = t; i < NBK; i += 256) cnt[i] = 0;
    __syncthreads();
    for (int i = t; i < m; i += 256) {
        int e = e0 + i;
        int d = (e < NE) ? edge_pa[NE + e] : NN + edge_ap[NE + (e - NE)];
        atomicAdd(&cnt[d >> 8], 1);
    }
    __syncthreads();
    for (int b = t; b < NBK; b += 256)
        if (cnt[b]) gpos[b] = atomicAdd(&bcur[b], cnt[b]);
    __syncthreads();
    for (int i = t; i < m; i += 256) {
        int e = e0 + i;
        int src, d;
        if (e < NE) { src = edge_pa[e]; d = edge_pa[NE + e]; }
        else        { int j = e - NE; src = edge_ap[j]; d = NN + edge_ap[NE + j]; }
        int p = atomicAdd(&gpos[d >> 8], 1);
        colt[p] = ((unsigned)src << 8) | (unsigned)(d & 255);
    }
}

// Pass 2: one block per bucket; rowptr cursors in LDS; stream the bucket's tmp
// items (coalesced) and scatter inside the bucket's ~12KB col window (L2-local).
// NOTE: 257 cursors but 256 threads -> strided init (bug fixed: cur[256] must load).
__global__ __launch_bounds__(256) void k_bucket2(const unsigned* __restrict__ colt,
                                                 const int* __restrict__ rpc, int* __restrict__ colc) {
    __shared__ int cur[257];
    int b = blockIdx.x, t = threadIdx.x;
    int node0 = b * 256;
    int nn2 = min(256, 2 * NN - node0);
    for (int i = t; i <= nn2; i += 256) cur[i] = rpc[node0 + i];
    __syncthreads();
    int g0 = cur[0], g1 = cur[nn2];
    __syncthreads();
    for (int i = g0 + t; i < g1; i += 256) {
        unsigned p = colt[i];
        int pos = atomicAdd(&cur[p & 255], 1);
        colc[pos] = (int)(p >> 8);
    }
}

// ---------- H = X @ W via MFMA (split-A for fp32-exact X) + fused dual dot ----------
__global__ __launch_bounds__(256) void k_gemm(const float* __restrict__ X, const __half* __restrict__ Wt,
                                              const float* __restrict__ v1, const float* __restrict__ v2,
                                              __half* __restrict__ Hout,
                                              float* __restrict__ o1, float* __restrict__ o2, int n) {
    int wave = threadIdx.x >> 6;
    int lane = threadIdx.x & 63;
    int r0 = blockIdx.x * 64 + wave * 16;
    int arow = r0 + (lane & 15);
    int kgrp = (lane >> 4) * 8;

    f32x4 acc[8] = {};
    float s1 = 0.f, s2 = 0.f;
#pragma unroll
    for (int ks = 0; ks < 4; ++ks) {
        int k0 = ks * 32 + kgrp;
        float xv[8];
        if (arow < n) {
            float4 x0 = *(const float4*)(X + (size_t)arow * HH + k0);
            float4 x1 = *(const float4*)(X + (size_t)arow * HH + k0 + 4);
            xv[0] = x0.x; xv[1] = x0.y; xv[2] = x0.z; xv[3] = x0.w;
            xv[4] = x1.x; xv[5] = x1.y; xv[6] = x1.z; xv[7] = x1.w;
        } else {
#pragma unroll
            for (int i = 0; i < 8; ++i) xv[i] = 0.f;
        }
        float4 va0 = *(const float4*)(v1 + k0), va1 = *(const float4*)(v1 + k0 + 4);
        float4 vb0 = *(const float4*)(v2 + k0), vb1 = *(const float4*)(v2 + k0 + 4);
        s1 += xv[0] * va0.x + xv[1] * va0.y + xv[2] * va0.z + xv[3] * va0.w
            + xv[4] * va1.x + xv[5] * va1.y + xv[6] * va1.z + xv[7] * va1.w;
        s2 += xv[0] * vb0.x + xv[1] * vb0.y + xv[2] * vb0.z + xv[3] * vb0.w
            + xv[4] * vb1.x + xv[5] * vb1.y + xv[6] * vb1.z + xv[7] * vb1.w;

        f16x8 ahi, alo;
#pragma unroll
        for (int i = 0; i < 8; ++i) {
            _Float16 h = (_Float16)xv[i];
            ahi[i] = h;
            alo[i] = (_Float16)(xv[i] - (float)h);
        }
#pragma unroll
        for (int nt = 0; nt < 8; ++nt) {
            const f16x8 b = *(const f16x8*)(Wt + ((size_t)(nt * 16 + (lane & 15))) * HH + k0);
            acc[nt] = __builtin_amdgcn_mfma_f32_16x16x32_f16(alo, b, acc[nt], 0, 0, 0);
            acc[nt] = __builtin_amdgcn_mfma_f32_16x16x32_f16(ahi, b, acc[nt], 0, 0, 0);
        }
    }

    s1 += __shfl_xor(s1, 16); s1 += __shfl_xor(s1, 32);
    s2 += __shfl_xor(s2, 16); s2 += __shfl_xor(s2, 32);
    if ((lane >> 4) == 0 && arow < n) { o1[arow] = s1; o2[arow] = s2; }

    int srow = r0 + (lane >> 4) * 4;
    int scol = lane & 15;
#pragma unroll
    for (int nt = 0; nt < 8; ++nt) {
#pragma unroll
        for (int reg = 0; reg < 4; ++reg) {
            int gr = srow + reg;
            if (gr < n) Hout[(size_t)gr * HH + nt * 16 + scol] = __float2half_rn(acc[nt][reg]);
        }
    }
}

// ---------- GAT aggregation, both edge types in one dispatch, 8-deep ILP ----------
__global__ __launch_bounds__(256) void k_aggregate2(const int* __restrict__ rpc, const int* __restrict__ colc,
                                                    const __half* __restrict__ H0, const __half* __restrict__ H1,
                                                    const float* __restrict__ as0, const float* __restrict__ ad0,
                                                    const float* __restrict__ as1, const float* __restrict__ ad1,
                                                    const float* __restrict__ bias0, const float* __restrict__ bias1,
                                                    float* __restrict__ XA, float* __restrict__ XP) {
    int w = (blockIdx.x * blockDim.x + threadIdx.x) >> 6;   // 0..2*NN-1
    int lane = threadIdx.x & 63;
    int type = (w >= NN);
    int node = type ? w - NN : w;
    const __half2* H2  = (const __half2*)(type ? H1 : H0);
    const float* a_s  = type ? as1 : as0;
    float add         = (type ? ad1 : ad0)[node];
    const float* bias = type ? bias1 : bias0;
    float* Xout       = type ? XP : XA;

    int base = rpc[w], end = rpc[w + 1];

    float den = 0.f;
    float2 acc = {0.f, 0.f};

    int j = base;
    for (; j + 8 <= end; j += 8) {
        int s[8]; float c[8]; __half2 h[8];
#pragma unroll
        for (int k = 0; k < 8; ++k) s[k] = colc[j + k];
#pragma unroll
        for (int k = 0; k < 8; ++k) c[k] = a_s[s[k]] + add;
#pragma unroll
        for (int k = 0; k < 8; ++k) h[k] = H2[(size_t)s[k] * (HH / 2) + lane];
#pragma unroll
        for (int k = 0; k < 8; ++k) {
            float cc = c[k];
            cc = cc > 0.f ? cc : NEG * cc;
            float e = __expf(cc);
            den += e;
            float2 f = __half22float2(h[k]);
            acc.x += e * f.x;
            acc.y += e * f.y;
        }
    }
    for (; j + 4 <= end; j += 4) {
        int s[4]; float c[4]; __half2 h[4];
#pragma unroll
        for (int k = 0; k < 4; ++k) s[k] = colc[j + k];
#pragma unroll
        for (int k = 0; k < 4; ++k) c[k] = a_s[s[k]] + add;
#pragma unroll
        for (int k = 0; k < 4; ++k) h[k] = H2[(size_t)s[k] * (HH / 2) + lane];
#pragma unroll
        for (int k = 0; k < 4; ++k) {
            float cc = c[k];
            cc = cc > 0.f ? cc : NEG * cc;
            float e = __expf(cc);
            den += e;
            float2 f = __half22float2(h[k]);
            acc.x += e * f.x;
            acc.y += e * f.y;
        }
    }
    for (; j < end; ++j) {
        int s = colc[j];
        float cc = a_s[s] + add;
        cc = cc > 0.f ? cc : NEG * cc;
        float e = __expf(cc);
        den += e;
        float2 f = __half22float2(H2[(size_t)s * (HH / 2) + lane]);
        acc.x += e * f.x;
        acc.y += e * f.y;
    }

    float inv = 1.f / (den + 1e-16f);
    float2 b = *(const float2*)(bias + lane * 2);
    float2 o;
    o.x = fmaxf(acc.x * inv + b.x, 0.f);
    o.y = fmaxf(acc.y * inv + b.y, 0.f);
    *(float2*)(Xout + (size_t)node * HH + lane * 2) = o;
}

// ---------- pooling: segment_max over sorted batch, 8 nodes in flight per block ----------
constexpr int POOL_CHUNK = 64;                       // nodes per block
__global__ __launch_bounds__(256) void k_pool(const float* __restrict__ XPf, const float* __restrict__ XAf,
                                              const int* __restrict__ batch_p, const int* __restrict__ batch_a,
                                              unsigned* __restrict__ pooled, int n, int blocksPerType) {
    int type = blockIdx.x / blocksPerType;
    int blk  = blockIdx.x % blocksPerType;
    const float* X = type ? XAf : XPf;
    const int* batch = type ? batch_a : batch_p;
    unsigned* pool = pooled + type * GG * HH;

    int sub  = threadIdx.x >> 5;                     // 0..7
    int lane = threadIdx.x & 31;                     // float4 index
    int i0 = blk * POOL_CHUNK + sub * (POOL_CHUNK / 8);
    if (i0 >= n) return;
    int i1 = min(i0 + POOL_CHUNK / 8, n);

    int g = batch[i0];
    float4 m = make_float4(0.f, 0.f, 0.f, 0.f);
    for (int i = i0; i < i1; ++i) {
        int gi = batch[i];
        if (gi != g) {
            unsigned* p = pool + g * HH + lane * 4;
            atomicMax(p + 0, __float_as_uint(m.x));
            atomicMax(p + 1, __float_as_uint(m.y));
            atomicMax(p + 2, __float_as_uint(m.z));
            atomicMax(p + 3, __float_as_uint(m.w));
            m = make_float4(0.f, 0.f, 0.f, 0.f);
            g = gi;
        }
        float4 x = *(const float4*)(X + (size_t)i * HH + lane * 4);
        m.x = fmaxf(m.x, x.x);
        m.y = fmaxf(m.y, x.y);
        m.z = fmaxf(m.z, x.z);
        m.w = fmaxf(m.w, x.w);
    }
    unsigned* p = pool + g * HH + lane * 4;
    atomicMax(p + 0, __float_as_uint(m.x));
    atomicMax(p + 1, __float_as_uint(m.y));
    atomicMax(p + 2, __float_as_uint(m.z));
    atomicMax(p + 3, __float_as_uint(m.w));
}

// ---------- final linear: [2][64][128] @ [128][16] + b ----------
__global__ void k_final(const unsigned* __restrict__ pooled, const float* __restrict__ linW,
                        const float* __restrict__ linb, float* __restrict__ out) {
    int idx = blockIdx.x * blockDim.x + threadIdx.x;
    if (idx >= 2 * GG * OC) return;
    int p = idx >> 10;            // which node type
    int g = (idx >> 4) & 63;
    int o = idx & 15;
    const unsigned* row = pooled + (size_t)(p * GG + g) * HH;
    float s = linb[o];
    for (int k = 0; k < HH; ++k) s += __uint_as_float(row[k]) * linW[k * OC + o];
    out[idx] = s;
}

extern "C" void kernel_launch(void* const* d_in, const int* in_sizes, int n_in,
                              void* d_out, int out_size, void* d_ws, size_t ws_size,
                              hipStream_t stream) {
    const float* x_paper  = (const float*)d_in[0];
    const float* x_author = (const float*)d_in[1];
    const int*   edge_pa  = (const int*)d_in[2];   // [2][E], row0=src(paper), row1=dst(author)
    const int*   edge_ap  = (const int*)d_in[3];
    const int*   batch_p  = (const int*)d_in[4];
    const int*   batch_a  = (const int*)d_in[5];
    const float* Wsrc     = (const float*)d_in[6];
    const float* Wdst     = (const float*)d_in[7];
    const float* att_src  = (const float*)d_in[8];
    const float* att_dst  = (const float*)d_in[9];
    const float* bias     = (const float*)d_in[10];
    const float* linW     = (const float*)d_in[11];
    const float* linb     = (const float*)d_in[12];
    float* out = (float*)d_out;

    size_t off = 0;
    char* base = (char*)d_ws;
    auto alloc = [&](size_t bytes) -> void* {
        void* p = base + off;
        off += (bytes + 255) & ~(size_t)255;
        return p;
    };
    __half* H0 = (__half*)alloc((size_t)NN * HH * 2);
    __half* H1 = (__half*)alloc((size_t)NN * HH * 2);
    float* XP  = (float*)alloc((size_t)NN * HH * 4);
    float* XA  = (float*)alloc((size_t)NN * HH * 4);
    float* as0 = (float*)alloc(NN * 4);
    float* ad0 = (float*)alloc(NN * 4);
    float* as1 = (float*)alloc(NN * 4);
    float* ad1 = (float*)alloc(NN * 4);
    float* vv  = (float*)alloc(8 * HH * 4);
    __half* Wt = (__half*)alloc(4 * HH * HH * 2);
    int* rpc  = (int*)alloc((2 * NN + 1) * 4);      // combined rowptr
    int* colc = (int*)alloc(2 * NE * 4);            // final col (src per edge)
    unsigned* colt = (unsigned*)alloc(2 * NE * 4);  // bucket-ordered tmp
    int* cnt  = (int*)alloc(2 * NN * 4);
    int* bsum = (int*)alloc(2048);
    int* bcur = (int*)alloc(NBK * 4);
    unsigned* pooled = (unsigned*)alloc(2 * GG * HH * 4);

    const int EB2  = (2 * NE + 255) / 256;   // 4688
    const int NBS2 = (2 * NN + 255) / 256;   // 391
    const int CB   = (2 * NE + 4095) / 4096; // 293 bucket1 blocks

    // ---- precompute attention vectors + fp16 transposed W ----
    k_prevec<<<8, 128, 0, stream>>>(Wsrc, Wdst, att_src, att_dst, vv);
    k_wcvt<<<512, 128, 0, stream>>>(Wsrc, Wt);

    // ---- combined CSR build for both edge types (bucketed two-pass) ----
    hipMemsetAsync(cnt, 0, 2 * NN * sizeof(int), stream);
    k_hist2<<<EB2, 256, 0, stream>>>(edge_pa + NE, edge_ap + NE, cnt);
    k_scan1<<<NBS2, 256, 0, stream>>>(cnt, bsum, 2 * NN);
    k_scan2<<<1, 512, 0, stream>>>(bsum, NBS2);
    k_scan3<<<NBS2, 256, 0, stream>>>(cnt, bsum, rpc, 2 * NN, 2 * NE);
    k_binit<<<(NBK + 255) / 256, 256, 0, stream>>>(rpc, bcur);
    k_bucket1<<<CB, 256, 0, stream>>>(edge_pa, edge_ap, bcur, colt);
    k_bucket2<<<NBK, 256, 0, stream>>>(colt, rpc, colc);

    // ---- GAT layers ----
    const float* xp = x_paper;
    const float* xa = x_author;
    const int GB = (NN + 63) / 64;           // 782
    for (int l = 0; l < LL; ++l) {
        int t0 = l * 2 + 0, t1 = l * 2 + 1;
        k_gemm<<<GB, 256, 0, stream>>>(xp, Wt + (size_t)t0 * HH * HH,
                                       vv + t0 * HH, vv + (4 + t1) * HH, H0, as0, ad1, NN);
        k_gemm<<<GB, 256, 0, stream>>>(xa, Wt + (size_t)t1 * HH * HH,
                                       vv + t1 * HH, vv + (4 + t0) * HH, H1, as1, ad0, NN);
        k_aggregate2<<<25000, 256, 0, stream>>>(rpc, colc, H0, H1, as0, ad0, as1, ad1,
                                                bias + t0 * HH, bias + t1 * HH, XA, XP);
        xp = XP; xa = XA;
    }

    // ---- pooling + final linear ----
    hipMemsetAsync(pooled, 0, 2 * GG * HH * sizeof(unsigned), stream);
    const int PB = (NN + POOL_CHUNK - 1) / POOL_CHUNK;   // 782 per type
    k_pool<<<PB * 2, 256, 0, stream>>>(XP, XA, batch_p, batch_a, pooled, NN, PB);
    k_final<<<8, 256, 0, stream>>>(pooled, linW, linb, out);
}